// Round 7
// baseline (1403.047 us; speedup 1.0000x reference)
//
#include <hip/hip_runtime.h>

#define NN 100000
#define NE 1250000
#define NB 2048
#define NBK 1563   // dst buckets of 64 nodes

typedef __attribute__((ext_vector_type(8))) short short8;
typedef __attribute__((ext_vector_type(4))) float floatx4;

__device__ inline unsigned short f2bf(float f) {
    unsigned u = __float_as_uint(f);
    u = u + 0x7fffu + ((u >> 16) & 1u);   // RNE
    return (unsigned short)(u >> 16);
}
__device__ inline float bf2f(unsigned short h) {
    return __uint_as_float(((unsigned)h) << 16);
}

// h[n][d] = sum_f atom_emb[f][x_feat[n][f]][d]
__global__ void atom_encode(const float* __restrict__ atom_emb,
                            const int* __restrict__ x_feat,
                            float* __restrict__ h) {
    int id = blockIdx.x * 256 + threadIdx.x;   // N*16 exact
    int n = id >> 4, q = id & 15;
    floatx4 acc = {0.f, 0.f, 0.f, 0.f};
    for (int f = 0; f < 9; f++) {
        int v = x_feat[n * 9 + f];
        const floatx4* p = (const floatx4*)(atom_emb + (size_t)(f * 128 + v) * 64);
        acc += p[q];
    }
    ((floatx4*)h)[(size_t)n * 16 + q] = acc;
}

// ---- CSR build ----
__global__ void deg_count(const int* __restrict__ ei, int* __restrict__ csr) {
    int e = blockIdx.x * 256 + threadIdx.x;
    if (e < NE) atomicAdd(&csr[ei[NE + e]], 1);
}

__global__ void scan_local(int* __restrict__ csr, int* __restrict__ bsum) {
    __shared__ int ls[256];
    int tid = threadIdx.x;
    int base = blockIdx.x * 1024 + tid * 4;
    int4 v = make_int4(0, 0, 0, 0);
    if (base + 3 < NN) {
        v = *(const int4*)(csr + base);
    } else {
        if (base + 0 < NN) v.x = csr[base + 0];
        if (base + 1 < NN) v.y = csr[base + 1];
        if (base + 2 < NN) v.z = csr[base + 2];
        if (base + 3 < NN) v.w = csr[base + 3];
    }
    int s = v.x + v.y + v.z + v.w;
    ls[tid] = s;
    __syncthreads();
    for (int d = 1; d < 256; d <<= 1) {
        int t = (tid >= d) ? ls[tid - d] : 0;
        __syncthreads();
        ls[tid] += t;
        __syncthreads();
    }
    if (tid == 255) bsum[blockIdx.x] = ls[255];
    int e0 = tid ? ls[tid - 1] : 0;
    int4 w;
    w.x = e0; w.y = e0 + v.x; w.z = w.y + v.y; w.w = w.z + v.z;
    if (base + 3 < NN) {
        *(int4*)(csr + base) = w;
    } else {
        if (base + 0 < NN) csr[base + 0] = w.x;
        if (base + 1 < NN) csr[base + 1] = w.y;
        if (base + 2 < NN) csr[base + 2] = w.z;
        if (base + 3 < NN) csr[base + 3] = w.w;
    }
}

__global__ void scan_bsum(int* __restrict__ bsum) {
    __shared__ int ls[128];
    int tid = threadIdx.x;
    int v = (tid < 98) ? bsum[tid] : 0;
    ls[tid] = v;
    __syncthreads();
    for (int d = 1; d < 128; d <<= 1) {
        int t = (tid >= d) ? ls[tid - d] : 0;
        __syncthreads();
        ls[tid] += t;
        __syncthreads();
    }
    if (tid < 98) bsum[tid] = tid ? ls[tid - 1] : 0;
}

__global__ void scan_add(int* __restrict__ csr, const int* __restrict__ bsum) {
    int off = bsum[blockIdx.x];
    int base = blockIdx.x * 1024 + threadIdx.x * 4;
    if (base + 3 < NN) {
        int4 v = *(const int4*)(csr + base);
        v.x += off; v.y += off; v.z += off; v.w += off;
        *(int4*)(csr + base) = v;
    } else {
        for (int i = 0; i < 4; i++)
            if (base + i < NN) csr[base + i] += off;
    }
}

// bucket base offsets = CSR start offset of node b*64 (csr holds START offsets here)
__global__ void bbase_k(const int* __restrict__ csr, int* __restrict__ bbase) {
    int b = blockIdx.x * 256 + threadIdx.x;
    if (b < NBK) bbase[b] = csr[b * 64];
}

// pass 1: append records to dst-bucket regions (dense frontier writes)
// record: src (17b) | attrs (9b) | dst_low (6b)
__global__ void bucket1(const int* __restrict__ ei, const int* __restrict__ ea,
                        const int* __restrict__ bbase, int* __restrict__ bcnt,
                        unsigned* __restrict__ tmp) {
    int e = blockIdx.x * 256 + threadIdx.x;
    if (e >= NE) return;
    int dst = ei[NE + e];
    int b = dst >> 6;
    unsigned at = (unsigned)(ea[e * 3] | (ea[e * 3 + 1] << 3) | (ea[e * 3 + 2] << 6));
    unsigned rec = (unsigned)ei[e] | (at << 17) | ((unsigned)(dst & 63) << 26);
    int pos = bbase[b] + atomicAdd(&bcnt[b], 1);
    tmp[pos] = rec;
}

// pass 2: one block per bucket; atomics on a 64-counter window (single-CU local),
// dense writes into the bucket's contiguous CSR slice. csr -> end offsets.
__global__ void bucket2(const unsigned* __restrict__ tmp, const int* __restrict__ bbase,
                        int* __restrict__ csr, unsigned* __restrict__ epack) {
    int b = blockIdx.x;
    int lo = bbase[b];
    int hi = (b + 1 < NBK) ? bbase[b + 1] : NE;
    int nb = b << 6;
    for (int i = lo + threadIdx.x; i < hi; i += 256) {
        unsigned rec = tmp[i];
        int dst = nb + (int)(rec >> 26);
        int pos = atomicAdd(&csr[dst], 1);
        epack[pos] = rec & 0x03FFFFFFu;
    }
}

// agg[n] = (1+eps)*h[n] + sum_{e: dst==n} relu(h[src_e] + bond(e))
template <bool HASBN>
__global__ void gather_k(const float* __restrict__ x, const float* __restrict__ bond_emb,
                         const float* __restrict__ eps, const int* __restrict__ csr,
                         const unsigned* __restrict__ epack, int l,
                         const double* __restrict__ stats, const float* __restrict__ bn_g,
                         const float* __restrict__ bn_b, float* __restrict__ agg) {
    __shared__ float be[24 * 64];
    __shared__ float ca[64], cb[64];
    int tid = threadIdx.x;
    const float* bsrc = bond_emb + (size_t)l * 1536;
    for (int i = tid; i < 1536; i += 256) be[i] = bsrc[i];
    if (tid < 64) {
        if (HASBN) {
            float mean = (float)(stats[tid] / NN);
            float var  = (float)(stats[64 + tid] / NN) - mean * mean;
            float a = bn_g[(l - 1) * 64 + tid] * rsqrtf(var + 1e-5f);
            ca[tid] = a;
            cb[tid] = bn_b[(l - 1) * 64 + tid] - mean * a;
        } else {
            ca[tid] = 1.f; cb[tid] = 0.f;
        }
    }
    __syncthreads();
    int id = blockIdx.x * 256 + tid;           // NN*16 exact
    int n = id >> 4, q = id & 15;
    float s = 1.0f + eps[l];
    floatx4 cav = *(const floatx4*)&ca[q * 4];
    floatx4 cbv = *(const floatx4*)&cb[q * 4];
    floatx4 xv = ((const floatx4*)x)[(size_t)n * 16 + q];
    if (HASBN) {
        xv[0] = fmaxf(cav[0] * xv[0] + cbv[0], 0.f);
        xv[1] = fmaxf(cav[1] * xv[1] + cbv[1], 0.f);
        xv[2] = fmaxf(cav[2] * xv[2] + cbv[2], 0.f);
        xv[3] = fmaxf(cav[3] * xv[3] + cbv[3], 0.f);
    }
    floatx4 acc = xv * s;
    int k0 = n ? csr[n - 1] : 0;
    int k1 = csr[n];
    const floatx4* beq = (const floatx4*)be;
    unsigned rec = (k0 < k1) ? epack[k0] : 0u;
    for (int k = k0; k < k1; k++) {
        unsigned cur = rec;
        if (k + 1 < k1) rec = epack[k + 1];
        int src = (int)(cur & 0x1FFFFu);
        floatx4 m = ((const floatx4*)x)[(size_t)src * 16 + q];
        if (HASBN) {
            m[0] = fmaxf(cav[0] * m[0] + cbv[0], 0.f);
            m[1] = fmaxf(cav[1] * m[1] + cbv[1], 0.f);
            m[2] = fmaxf(cav[2] * m[2] + cbv[2], 0.f);
            m[3] = fmaxf(cav[3] * m[3] + cbv[3], 0.f);
        }
        m += beq[((cur >> 17) & 7u) * 16 + q];
        m += beq[(8 + ((cur >> 20) & 7u)) * 16 + q];
        m += beq[(16 + ((cur >> 23) & 7u)) * 16 + q];
        acc[0] += fmaxf(m[0], 0.f);
        acc[1] += fmaxf(m[1], 0.f);
        acc[2] += fmaxf(m[2], 0.f);
        acc[3] += fmaxf(m[3], 0.f);
    }
    ((floatx4*)agg)[(size_t)n * 16 + q] = acc;
}

// weights -> split bf16 transposed
__global__ void wcvt(const float* __restrict__ W1, const float* __restrict__ W2,
                     unsigned short* __restrict__ w1h, unsigned short* __restrict__ w1l,
                     unsigned short* __restrict__ w2h, unsigned short* __restrict__ w2l) {
    int id = blockIdx.x * 256 + threadIdx.x;
    if (id < 32768) {
        int l = id >> 13, rem = id & 8191, c = rem >> 6, k = rem & 63;
        float w = W1[l * 8192 + k * 128 + c];
        unsigned short hh = f2bf(w);
        w1h[id] = hh; w1l[id] = f2bf(w - bf2f(hh));
    } else {
        int id2 = id - 32768;
        int l = id2 >> 13, rem = id2 & 8191, c = rem >> 7, k = rem & 127;
        float w = W2[l * 8192 + k * 64 + c];
        unsigned short hh = f2bf(w);
        w2h[id2] = hh; w2l[id2] = f2bf(w - bf2f(hh));
    }
}

#define MFMA __builtin_amdgcn_mfma_f32_16x16x32_bf16

// Gram pass: G_hh = Zh^T Zh, G_hl = Zh^T Zl (64x64 each, fp32 atomic accumulate),
// plus column sums of z. Replaces the redundant GEMM1 stats pass.
#define ZS 264   // LDS stride in shorts (256 + 8 pad), 16B-aligned rows
__launch_bounds__(256)
__global__ void zstat(const float* __restrict__ z, float* __restrict__ G,
                      float* __restrict__ zsum) {
    __shared__ char smem[67584];
    unsigned short* zh = (unsigned short*)smem;            // 64 x ZS
    unsigned short* zl = zh + 64 * ZS;
    int tid = threadIdx.x;
    int c2 = tid & 31;            // col-pair id
    int nof = tid >> 5;           // node sub-offset 0..7
    int wv = tid >> 6, lane = tid & 63, m = lane & 15, qd = lane >> 4;
    float2 csum = make_float2(0.f, 0.f);
    floatx4 acc[8];               // 4 j-tiles x {hh, hl}
    for (int t = 0; t < 8; t++) acc[t] = (floatx4){0.f, 0.f, 0.f, 0.f};
    for (int chunk = blockIdx.x; chunk < 391; chunk += 196) {
        int base = chunk * 256;
        for (int it = 0; it < 32; it++) {
            int n = it * 8 + nof;
            int node = base + n;
            float2 v = make_float2(0.f, 0.f);
            if (node < NN) v = ((const float2*)z)[(size_t)node * 32 + c2];
            csum.x += v.x; csum.y += v.y;
            unsigned short hx = f2bf(v.x), hy = f2bf(v.y);
            zh[(2 * c2) * ZS + n] = hx;
            zh[(2 * c2 + 1) * ZS + n] = hy;
            zl[(2 * c2) * ZS + n] = f2bf(v.x - bf2f(hx));
            zl[(2 * c2 + 1) * ZS + n] = f2bf(v.y - bf2f(hy));
        }
        __syncthreads();
        for (int kc = 0; kc < 8; kc++) {
            short8 ah = *(const short8*)&zh[(wv * 16 + m) * ZS + kc * 32 + qd * 8];
            for (int j = 0; j < 4; j++) {
                short8 bh = *(const short8*)&zh[(j * 16 + m) * ZS + kc * 32 + qd * 8];
                short8 bl = *(const short8*)&zl[(j * 16 + m) * ZS + kc * 32 + qd * 8];
                acc[j * 2]     = MFMA(ah, bh, acc[j * 2], 0, 0, 0);
                acc[j * 2 + 1] = MFMA(ah, bl, acc[j * 2 + 1], 0, 0, 0);
            }
        }
        __syncthreads();
    }
    for (int j = 0; j < 4; j++)
        for (int r = 0; r < 4; r++) {
            int idx = (wv * 16 + qd * 4 + r) * 64 + j * 16 + m;
            atomicAdd(&G[idx], acc[j * 2][r]);
            atomicAdd(&G[4096 + idx], acc[j * 2 + 1][r]);
        }
    float* red = (float*)smem;     // overlay (all MFMA reads done)
    red[tid] = csum.x; red[256 + tid] = csum.y;
    __syncthreads();
    if (tid < 32) {
        float sx = 0.f, sy = 0.f;
        for (int k = 0; k < 8; k++) { sx += red[k * 32 + tid]; sy += red[256 + k * 32 + tid]; }
        atomicAdd(&zsum[2 * tid], sx);
        atomicAdd(&zsum[2 * tid + 1], sy);
    }
}

// stats1 from Gram: sum_c = zsum.w_c + N b_c ; sumsq_c = w^T Ghh w + 2 w^T Ghl w + 2 b (zsum.w) + N b^2
__launch_bounds__(1024)
__global__ void bn1stat(const float* __restrict__ W1, const float* __restrict__ b1,
                        const float* __restrict__ G, const float* __restrict__ zsum,
                        int l, double* __restrict__ stats) {
    __shared__ float wsh[128 * 64];    // w[c][k]
    __shared__ float redq[1024];
    int tid = threadIdx.x;
    for (int idx = tid; idx < 8192; idx += 1024) {
        int k = idx >> 7, c = idx & 127;
        wsh[c * 64 + k] = W1[l * 8192 + idx];
    }
    __syncthreads();
    int c = tid & 127, s = tid >> 7;   // 8 i-slices per column
    const float* wc = &wsh[c * 64];
    float q = 0.f;
    for (int i = s * 8; i < s * 8 + 8; i++) {
        float dh = 0.f, dl = 0.f;
        const float* gh = &G[i * 64];
        const float* gl = &G[4096 + i * 64];
        for (int j = 0; j < 64; j++) {
            dh += gh[j] * wc[j];
            dl += gl[j] * wc[j];
        }
        q += wc[i] * (dh + 2.f * dl);
    }
    redq[tid] = q;
    __syncthreads();
    if (tid < 128) {
        float qq = 0.f;
        for (int ss = 0; ss < 8; ss++) qq += redq[ss * 128 + tid];
        const float* wcc = &wsh[tid * 64];
        float s1 = 0.f;
        for (int k = 0; k < 64; k++) s1 += zsum[k] * wcc[k];
        float bc = b1[l * 128 + tid];
        stats[tid] = (double)s1 + (double)NN * bc;
        stats[128 + tid] = (double)qq + 2.0 * bc * s1 + (double)NN * bc * bc;
    }
}

// Fused MLP: z -> GEMM1 -> bn1+relu -> GEMM2 -> t2 (+ fused t2 colstats)
__launch_bounds__(256)
__global__ void mlp_fused(const float* __restrict__ z,
                          const unsigned short* __restrict__ w1h, const unsigned short* __restrict__ w1l,
                          const float* __restrict__ b1,
                          const unsigned short* __restrict__ w2h, const unsigned short* __restrict__ w2l,
                          const float* __restrict__ b2,
                          const float* __restrict__ bn_g, const float* __restrict__ bn_b,
                          const double* __restrict__ stats1, int l,
                          float* __restrict__ t2, double* __restrict__ stats2) {
    __shared__ char smem[70656];
    unsigned short* zbh = (unsigned short*)smem;
    unsigned short* zbl = zbh + 64 * 72;
    unsigned short* wth = zbl + 64 * 72;
    unsigned short* wtl = wth + 128 * 72;
    unsigned short* rbh  = (unsigned short*)smem;
    unsigned short* rbl  = rbh + 64 * 136;
    unsigned short* w2th = rbl + 64 * 136;
    unsigned short* w2tl = w2th + 64 * 136;
    float* ca = (float*)(smem + 69632);
    float* cb = ca + 128;
    int tid = threadIdx.x;
    int base = blockIdx.x * 64;

    if (tid < 128) {
        float mean = (float)(stats1[tid] / NN);
        float var  = (float)(stats1[128 + tid] / NN) - mean * mean;
        float a = bn_g[l * 128 + tid] * rsqrtf(var + 1e-5f);
        ca[tid] = a;
        cb[tid] = bn_b[l * 128 + tid] - mean * a + a * b1[l * 128 + tid];
    }
    const unsigned short* wsh = w1h + l * 8192;
    const unsigned short* wsl = w1l + l * 8192;
    for (int it = 0; it < 4; it++) {
        int chunk = it * 256 + tid;
        int c = chunk >> 3, k0 = (chunk & 7) * 8;
        *(uint4*)&wth[c * 72 + k0] = *(const uint4*)(wsh + chunk * 8);
        *(uint4*)&wtl[c * 72 + k0] = *(const uint4*)(wsl + chunk * 8);
    }
    for (int it = 0; it < 8; it++) {
        int idx2 = (it * 256 + tid) * 2;
        int n = idx2 >> 6, col = idx2 & 63;
        int node = base + n;
        float2 v = make_float2(0.f, 0.f);
        if (node < NN) v = ((const float2*)z)[(size_t)node * 32 + (col >> 1)];
        unsigned short hx = f2bf(v.x), hy = f2bf(v.y);
        zbh[n * 72 + col] = hx;     zbh[n * 72 + col + 1] = hy;
        zbl[n * 72 + col] = f2bf(v.x - bf2f(hx));
        zbl[n * 72 + col + 1] = f2bf(v.y - bf2f(hy));
    }
    const unsigned short* w2sh = w2h + l * 8192;
    const unsigned short* w2sl = w2l + l * 8192;
    uint4 preH[4], preL[4];
    for (int it = 0; it < 4; it++) {
        preH[it] = *(const uint4*)(w2sh + (it * 256 + tid) * 8);
        preL[it] = *(const uint4*)(w2sl + (it * 256 + tid) * 8);
    }
    __syncthreads();
    int wv = tid >> 6, lane = tid & 63, m = lane & 15, qd = lane >> 4;
    short8 ah0 = *(const short8*)&zbh[(wv * 16 + m) * 72 + qd * 8];
    short8 ah1 = *(const short8*)&zbh[(wv * 16 + m) * 72 + 32 + qd * 8];
    short8 al0 = *(const short8*)&zbl[(wv * 16 + m) * 72 + qd * 8];
    short8 al1 = *(const short8*)&zbl[(wv * 16 + m) * 72 + 32 + qd * 8];
    floatx4 acc1[8];
    for (int t = 0; t < 8; t++) {
        short8 bh0 = *(const short8*)&wth[(t * 16 + m) * 72 + qd * 8];
        short8 bh1 = *(const short8*)&wth[(t * 16 + m) * 72 + 32 + qd * 8];
        short8 bl0 = *(const short8*)&wtl[(t * 16 + m) * 72 + qd * 8];
        short8 bl1 = *(const short8*)&wtl[(t * 16 + m) * 72 + 32 + qd * 8];
        floatx4 c0 = {0.f, 0.f, 0.f, 0.f};
        c0 = MFMA(ah0, bh0, c0, 0, 0, 0);
        c0 = MFMA(ah0, bl0, c0, 0, 0, 0);
        c0 = MFMA(al0, bh0, c0, 0, 0, 0);
        c0 = MFMA(ah1, bh1, c0, 0, 0, 0);
        c0 = MFMA(ah1, bl1, c0, 0, 0, 0);
        c0 = MFMA(al1, bh1, c0, 0, 0, 0);
        acc1[t] = c0;
    }
    __syncthreads();
    for (int it = 0; it < 4; it++) {
        int chunk = it * 256 + tid;
        int c = chunk >> 4, k0 = (chunk & 15) * 8;
        *(uint4*)&w2th[c * 136 + k0] = preH[it];
        *(uint4*)&w2tl[c * 136 + k0] = preL[it];
    }
    for (int t = 0; t < 8; t++) {
        int col = t * 16 + m;
        float a = ca[col], b = cb[col];
        for (int r = 0; r < 4; r++) {
            int row = wv * 16 + qd * 4 + r;
            float rv = fmaxf(a * acc1[t][r] + b, 0.f);
            unsigned short hh = f2bf(rv);
            rbh[row * 136 + col] = hh;
            rbl[row * 136 + col] = f2bf(rv - bf2f(hh));
        }
    }
    __syncthreads();
    short8 ah[4], al[4];
    for (int kh = 0; kh < 4; kh++) {
        ah[kh] = *(const short8*)&rbh[(wv * 16 + m) * 136 + kh * 32 + qd * 8];
        al[kh] = *(const short8*)&rbl[(wv * 16 + m) * 136 + kh * 32 + qd * 8];
    }
    floatx4 acc2[4];
    for (int t = 0; t < 4; t++) {
        floatx4 c0 = {0.f, 0.f, 0.f, 0.f};
        for (int kh = 0; kh < 4; kh++) {
            short8 bh = *(const short8*)&w2th[(t * 16 + m) * 136 + kh * 32 + qd * 8];
            short8 bl = *(const short8*)&w2tl[(t * 16 + m) * 136 + kh * 32 + qd * 8];
            c0 = MFMA(ah[kh], bh, c0, 0, 0, 0);
            c0 = MFMA(ah[kh], bl, c0, 0, 0, 0);
            c0 = MFMA(al[kh], bh, c0, 0, 0, 0);
        }
        acc2[t] = c0;
    }
    __syncthreads();
    float* redS = (float*)smem;
    float* redQ = redS + 1024;
    const float* bias = b2 + l * 64;
    int g = wv * 4 + qd;
    for (int t = 0; t < 4; t++) {
        int col = t * 16 + m;
        float bv = bias[col];
        float s = 0.f, ss = 0.f;
        for (int r = 0; r < 4; r++) {
            int node = base + wv * 16 + qd * 4 + r;
            if (node < NN) {
                float v = acc2[t][r] + bv;
                t2[(size_t)node * 64 + col] = v;
                s += v; ss += v * v;
            }
        }
        redS[col * 16 + g] = s;
        redQ[col * 16 + g] = ss;
    }
    __syncthreads();
    if (tid < 64) {
        float s = 0.f, ss = 0.f;
        for (int gg = 0; gg < 16; gg++) { s += redS[tid * 16 + gg]; ss += redQ[tid * 16 + gg]; }
        atomicAdd(&stats2[tid], (double)s);
        atomicAdd(&stats2[64 + tid], (double)ss);
    }
}

__global__ void bnapply_last(const float* __restrict__ t2, const float* __restrict__ bn_g,
                             const float* __restrict__ bn_b, const double* __restrict__ stats,
                             float* __restrict__ out, float* __restrict__ gsum,
                             float* __restrict__ gcnt, const int* __restrict__ batch) {
    __shared__ float ca[64], cb[64];
    int tid = threadIdx.x;
    if (tid < 64) {
        float mean = (float)(stats[tid] / NN);
        float var  = (float)(stats[64 + tid] / NN) - mean * mean;
        float a = bn_g[3 * 64 + tid] * rsqrtf(var + 1e-5f);
        ca[tid] = a;
        cb[tid] = bn_b[3 * 64 + tid] - mean * a;
    }
    __syncthreads();
    size_t base = (size_t)blockIdx.x * 4096;
    for (int it = 0; it < 16; it++) {
        size_t idx = base + it * 256 + tid;
        if (idx >= (size_t)NN * 64) return;
        int c = (int)(idx & 63);
        float v = ca[c] * t2[idx] + cb[c];
        out[idx] = v;
        int g = batch[idx >> 6];
        atomicAdd(&gsum[(size_t)g * 64 + c], v);
        if (c == 0) atomicAdd(&gcnt[g], 1.0f);
    }
}

__global__ void pool_div(const float* __restrict__ gsum, const float* __restrict__ gcnt,
                         float* __restrict__ out) {
    int id = blockIdx.x * 256 + threadIdx.x;
    int g = id >> 6;
    out[(size_t)NN * 64 + id] = gsum[id] / (gcnt[g] + 1e-9f);
}

extern "C" void kernel_launch(void* const* d_in, const int* in_sizes, int n_in,
                              void* d_out, int out_size, void* d_ws, size_t ws_size,
                              hipStream_t stream) {
    const float* atom_emb = (const float*)d_in[0];
    const float* bond_emb = (const float*)d_in[1];
    const float* eps      = (const float*)d_in[2];
    const float* W1       = (const float*)d_in[3];
    const float* b1       = (const float*)d_in[4];
    const float* bn1_g    = (const float*)d_in[5];
    const float* bn1_b    = (const float*)d_in[6];
    const float* W2       = (const float*)d_in[7];
    const float* b2       = (const float*)d_in[8];
    const float* bn2_g    = (const float*)d_in[9];
    const float* bn2_b    = (const float*)d_in[10];
    const int* x_feat     = (const int*)d_in[11];
    const int* edge_index = (const int*)d_in[12];
    const int* edge_attr  = (const int*)d_in[13];
    const int* batch      = (const int*)d_in[14];
    float* out = (float*)d_out;

    char* ws = (char*)d_ws;
    // ---- zero region (one memset) ----
    double* stats = (double*)ws;  ws += 2048 * 8;            // 8 slots x 256 doubles
    float* gsum   = (float*)ws;   ws += (size_t)NB * 64 * 4;
    float* gcnt   = (float*)ws;   ws += NB * 4;
    int* csr      = (int*)ws;     ws += (size_t)NN * 4;
    int* bcnt     = (int*)ws;     ws += 1600 * 4;
    float* G      = (float*)ws;   ws += (size_t)4 * 8192 * 4;  // per-layer [Ghh|Ghl]
    float* zsum   = (float*)ws;   ws += 4 * 64 * 4;
    size_t zbytes = (size_t)(ws - (char*)d_ws);
    // ---- rest ----
    int* bsum       = (int*)ws;       ws += 128 * 4;
    int* bbase      = (int*)ws;       ws += 1600 * 4;
    unsigned* tmp   = (unsigned*)ws;  ws += (size_t)NE * 4;
    unsigned* epack = (unsigned*)ws;  ws += (size_t)NE * 4;
    float* xbuf = (float*)ws;     ws += (size_t)NN * 64 * 4;   // h (l=0) / t2 (l>=1)
    float* agg  = (float*)ws;     ws += (size_t)NN * 64 * 4;
    unsigned short* w1h = (unsigned short*)ws; ws += 32768 * 2;
    unsigned short* w1l = (unsigned short*)ws; ws += 32768 * 2;
    unsigned short* w2h = (unsigned short*)ws; ws += 32768 * 2;
    unsigned short* w2l = (unsigned short*)ws; ws += 32768 * 2;

    hipMemsetAsync((void*)stats, 0, zbytes, stream);

    wcvt<<<256, 256, 0, stream>>>(W1, W2, w1h, w1l, w2h, w2l);
    deg_count<<<4883, 256, 0, stream>>>(edge_index, csr);
    scan_local<<<98, 256, 0, stream>>>(csr, bsum);
    scan_bsum<<<1, 128, 0, stream>>>(bsum);
    scan_add<<<98, 256, 0, stream>>>(csr, bsum);
    bbase_k<<<7, 256, 0, stream>>>(csr, bbase);
    bucket1<<<4883, 256, 0, stream>>>(edge_index, edge_attr, bbase, bcnt, tmp);
    bucket2<<<NBK, 256, 0, stream>>>(tmp, bbase, csr, epack);
    atom_encode<<<6250, 256, 0, stream>>>(atom_emb, x_feat, xbuf);

    for (int l = 0; l < 4; l++) {
        double* s1 = stats + (size_t)(l * 2) * 256;
        double* s2 = stats + (size_t)(l * 2 + 1) * 256;
        if (l == 0) {
            gather_k<false><<<6250, 256, 0, stream>>>(xbuf, bond_emb, eps, csr, epack, l,
                                                      nullptr, nullptr, nullptr, agg);
        } else {
            double* sp = stats + (size_t)((l - 1) * 2 + 1) * 256;
            gather_k<true><<<6250, 256, 0, stream>>>(xbuf, bond_emb, eps, csr, epack, l,
                                                     sp, bn2_g, bn2_b, agg);
        }
        zstat<<<196, 256, 0, stream>>>(agg, G + (size_t)l * 8192, zsum + l * 64);
        bn1stat<<<1, 1024, 0, stream>>>(W1, b1, G + (size_t)l * 8192, zsum + l * 64, l, s1);
        mlp_fused<<<1563, 256, 0, stream>>>(agg, w1h, w1l, b1, w2h, w2l, b2,
                                            bn1_g, bn1_b, s1, l, xbuf, s2);
    }
    bnapply_last<<<1563, 256, 0, stream>>>(xbuf, bn2_g, bn2_b,
                                           stats + (size_t)(3 * 2 + 1) * 256,
                                           out, gsum, gcnt, batch);
    pool_div<<<512, 256, 0, stream>>>(gsum, gcnt, out);
}

// Round 8
// 1324.967 us; speedup vs baseline: 1.0589x; 1.0589x over previous
//
#include <hip/hip_runtime.h>

#define NN 100000
#define NE 1250000
#define NB 2048
#define NZB 391    // zstat blocks (391*256 = 100096 >= NN)

typedef __attribute__((ext_vector_type(8))) short short8;
typedef __attribute__((ext_vector_type(4))) float floatx4;

__device__ inline unsigned short f2bf(float f) {
    unsigned u = __float_as_uint(f);
    u = u + 0x7fffu + ((u >> 16) & 1u);   // RNE
    return (unsigned short)(u >> 16);
}
__device__ inline float bf2f(unsigned short h) {
    return __uint_as_float(((unsigned)h) << 16);
}

// h[n][d] = sum_f atom_emb[f][x_feat[n][f]][d]
__global__ void atom_encode(const float* __restrict__ atom_emb,
                            const int* __restrict__ x_feat,
                            float* __restrict__ h) {
    int id = blockIdx.x * 256 + threadIdx.x;   // N*16 exact
    int n = id >> 4, q = id & 15;
    floatx4 acc = {0.f, 0.f, 0.f, 0.f};
    for (int f = 0; f < 9; f++) {
        int v = x_feat[n * 9 + f];
        const floatx4* p = (const floatx4*)(atom_emb + (size_t)(f * 128 + v) * 64);
        acc += p[q];
    }
    ((floatx4*)h)[(size_t)n * 16 + q] = acc;
}

// ---- CSR build ----
__global__ void deg_count(const int* __restrict__ ei, int* __restrict__ csr) {
    int e = blockIdx.x * 256 + threadIdx.x;
    if (e < NE) atomicAdd(&csr[ei[NE + e]], 1);
}

__global__ void scan_local(int* __restrict__ csr, int* __restrict__ bsum) {
    __shared__ int ls[256];
    int tid = threadIdx.x;
    int base = blockIdx.x * 1024 + tid * 4;
    int4 v = make_int4(0, 0, 0, 0);
    if (base + 3 < NN) {
        v = *(const int4*)(csr + base);
    } else {
        if (base + 0 < NN) v.x = csr[base + 0];
        if (base + 1 < NN) v.y = csr[base + 1];
        if (base + 2 < NN) v.z = csr[base + 2];
        if (base + 3 < NN) v.w = csr[base + 3];
    }
    int s = v.x + v.y + v.z + v.w;
    ls[tid] = s;
    __syncthreads();
    for (int d = 1; d < 256; d <<= 1) {
        int t = (tid >= d) ? ls[tid - d] : 0;
        __syncthreads();
        ls[tid] += t;
        __syncthreads();
    }
    if (tid == 255) bsum[blockIdx.x] = ls[255];
    int e0 = tid ? ls[tid - 1] : 0;
    int4 w;
    w.x = e0; w.y = e0 + v.x; w.z = w.y + v.y; w.w = w.z + v.z;
    if (base + 3 < NN) {
        *(int4*)(csr + base) = w;
    } else {
        if (base + 0 < NN) csr[base + 0] = w.x;
        if (base + 1 < NN) csr[base + 1] = w.y;
        if (base + 2 < NN) csr[base + 2] = w.z;
        if (base + 3 < NN) csr[base + 3] = w.w;
    }
}

__global__ void scan_bsum(int* __restrict__ bsum) {
    __shared__ int ls[128];
    int tid = threadIdx.x;
    int v = (tid < 98) ? bsum[tid] : 0;
    ls[tid] = v;
    __syncthreads();
    for (int d = 1; d < 128; d <<= 1) {
        int t = (tid >= d) ? ls[tid - d] : 0;
        __syncthreads();
        ls[tid] += t;
        __syncthreads();
    }
    if (tid < 98) bsum[tid] = tid ? ls[tid - 1] : 0;
}

__global__ void scan_add(int* __restrict__ csr, const int* __restrict__ bsum) {
    int off = bsum[blockIdx.x];
    int base = blockIdx.x * 1024 + threadIdx.x * 4;
    if (base + 3 < NN) {
        int4 v = *(const int4*)(csr + base);
        v.x += off; v.y += off; v.z += off; v.w += off;
        *(int4*)(csr + base) = v;
    } else {
        for (int i = 0; i < 4; i++)
            if (base + i < NN) csr[base + i] += off;
    }
}

// packed record: src (17b) | a0 (3b) | a1 (3b) | a2 (3b)
__global__ void csr_fill(const int* __restrict__ ei, const int* __restrict__ ea,
                         int* __restrict__ csr, unsigned* __restrict__ epack) {
    int e = blockIdx.x * 256 + threadIdx.x;
    if (e >= NE) return;
    int dst = ei[NE + e];
    int pos = atomicAdd(&csr[dst], 1);
    unsigned at = (unsigned)(ea[e * 3] | (ea[e * 3 + 1] << 3) | (ea[e * 3 + 2] << 6));
    epack[pos] = (unsigned)ei[e] | (at << 17);
}

// agg[n] = (1+eps)*h[n] + sum_{e: dst==n} relu(h[src_e] + bond(e))
template <bool HASBN>
__global__ void gather_k(const float* __restrict__ x, const float* __restrict__ bond_emb,
                         const float* __restrict__ eps, const int* __restrict__ csr,
                         const unsigned* __restrict__ epack, int l,
                         const double* __restrict__ stats, const float* __restrict__ bn_g,
                         const float* __restrict__ bn_b, float* __restrict__ agg) {
    __shared__ float be[24 * 64];
    __shared__ float ca[64], cb[64];
    int tid = threadIdx.x;
    const float* bsrc = bond_emb + (size_t)l * 1536;
    for (int i = tid; i < 1536; i += 256) be[i] = bsrc[i];
    if (tid < 64) {
        if (HASBN) {
            float mean = (float)(stats[tid] / NN);
            float var  = (float)(stats[64 + tid] / NN) - mean * mean;
            float a = bn_g[(l - 1) * 64 + tid] * rsqrtf(var + 1e-5f);
            ca[tid] = a;
            cb[tid] = bn_b[(l - 1) * 64 + tid] - mean * a;
        } else {
            ca[tid] = 1.f; cb[tid] = 0.f;
        }
    }
    __syncthreads();
    int id = blockIdx.x * 256 + tid;           // NN*16 exact
    int n = id >> 4, q = id & 15;
    float s = 1.0f + eps[l];
    floatx4 cav = *(const floatx4*)&ca[q * 4];
    floatx4 cbv = *(const floatx4*)&cb[q * 4];
    floatx4 xv = ((const floatx4*)x)[(size_t)n * 16 + q];
    if (HASBN) {
        xv[0] = fmaxf(cav[0] * xv[0] + cbv[0], 0.f);
        xv[1] = fmaxf(cav[1] * xv[1] + cbv[1], 0.f);
        xv[2] = fmaxf(cav[2] * xv[2] + cbv[2], 0.f);
        xv[3] = fmaxf(cav[3] * xv[3] + cbv[3], 0.f);
    }
    floatx4 acc = xv * s;
    int k0 = n ? csr[n - 1] : 0;
    int k1 = csr[n];
    const floatx4* beq = (const floatx4*)be;
    unsigned rec = (k0 < k1) ? epack[k0] : 0u;
    for (int k = k0; k < k1; k++) {
        unsigned cur = rec;
        if (k + 1 < k1) rec = epack[k + 1];
        int src = (int)(cur & 0x1FFFFu);
        floatx4 m = ((const floatx4*)x)[(size_t)src * 16 + q];
        if (HASBN) {
            m[0] = fmaxf(cav[0] * m[0] + cbv[0], 0.f);
            m[1] = fmaxf(cav[1] * m[1] + cbv[1], 0.f);
            m[2] = fmaxf(cav[2] * m[2] + cbv[2], 0.f);
            m[3] = fmaxf(cav[3] * m[3] + cbv[3], 0.f);
        }
        m += beq[((cur >> 17) & 7u) * 16 + q];
        m += beq[(8 + ((cur >> 20) & 7u)) * 16 + q];
        m += beq[(16 + ((cur >> 23) & 7u)) * 16 + q];
        acc[0] += fmaxf(m[0], 0.f);
        acc[1] += fmaxf(m[1], 0.f);
        acc[2] += fmaxf(m[2], 0.f);
        acc[3] += fmaxf(m[3], 0.f);
    }
    ((floatx4*)agg)[(size_t)n * 16 + q] = acc;
}

// weights -> split bf16 transposed
__global__ void wcvt(const float* __restrict__ W1, const float* __restrict__ W2,
                     unsigned short* __restrict__ w1h, unsigned short* __restrict__ w1l,
                     unsigned short* __restrict__ w2h, unsigned short* __restrict__ w2l) {
    int id = blockIdx.x * 256 + threadIdx.x;
    if (id < 32768) {
        int l = id >> 13, rem = id & 8191, c = rem >> 6, k = rem & 63;
        float w = W1[l * 8192 + k * 128 + c];
        unsigned short hh = f2bf(w);
        w1h[id] = hh; w1l[id] = f2bf(w - bf2f(hh));
    } else {
        int id2 = id - 32768;
        int l = id2 >> 13, rem = id2 & 8191, c = rem >> 7, k = rem & 127;
        float w = W2[l * 8192 + k * 64 + c];
        unsigned short hh = f2bf(w);
        w2h[id2] = hh; w2l[id2] = f2bf(w - bf2f(hh));
    }
}

#define MFMA __builtin_amdgcn_mfma_f32_16x16x32_bf16

// Gram pass: per-block partials of G_hh = Zh^T Zh, G_hl = Zh^T Zl over 256 nodes.
// NO global atomics (round-7 lesson): each output element lives in exactly one lane,
// blocks write a clean 32 KB partial; greduce sums them.
#define ZS 264   // LDS stride in shorts (256 + 8 pad)
__launch_bounds__(256)
__global__ void zstat(const float* __restrict__ z, float* __restrict__ Gpart,
                      float* __restrict__ zsum) {
    __shared__ char smem[67584];
    unsigned short* zh = (unsigned short*)smem;            // 64 x ZS
    unsigned short* zl = zh + 64 * ZS;
    int tid = threadIdx.x;
    int c2 = tid & 31;            // col-pair id
    int nof = tid >> 5;           // node sub-offset 0..7
    int wv = tid >> 6, lane = tid & 63, m = lane & 15, qd = lane >> 4;
    float2 csum = make_float2(0.f, 0.f);
    floatx4 acc[8];               // 4 j-tiles x {hh, hl}
    for (int t = 0; t < 8; t++) acc[t] = (floatx4){0.f, 0.f, 0.f, 0.f};
    int base = blockIdx.x * 256;
    for (int it = 0; it < 32; it++) {
        int n = it * 8 + nof;
        int node = base + n;
        float2 v = make_float2(0.f, 0.f);
        if (node < NN) v = ((const float2*)z)[(size_t)node * 32 + c2];
        csum.x += v.x; csum.y += v.y;
        unsigned short hx = f2bf(v.x), hy = f2bf(v.y);
        zh[(2 * c2) * ZS + n] = hx;
        zh[(2 * c2 + 1) * ZS + n] = hy;
        zl[(2 * c2) * ZS + n] = f2bf(v.x - bf2f(hx));
        zl[(2 * c2 + 1) * ZS + n] = f2bf(v.y - bf2f(hy));
    }
    __syncthreads();
    for (int kc = 0; kc < 8; kc++) {
        short8 ah = *(const short8*)&zh[(wv * 16 + m) * ZS + kc * 32 + qd * 8];
        for (int j = 0; j < 4; j++) {
            short8 bh = *(const short8*)&zh[(j * 16 + m) * ZS + kc * 32 + qd * 8];
            short8 bl = *(const short8*)&zl[(j * 16 + m) * ZS + kc * 32 + qd * 8];
            acc[j * 2]     = MFMA(ah, bh, acc[j * 2], 0, 0, 0);
            acc[j * 2 + 1] = MFMA(ah, bl, acc[j * 2 + 1], 0, 0, 0);
        }
    }
    float* gp = Gpart + (size_t)blockIdx.x * 8192;
    for (int j = 0; j < 4; j++)
        for (int r = 0; r < 4; r++) {
            int idx = (wv * 16 + qd * 4 + r) * 64 + j * 16 + m;
            gp[idx] = acc[j * 2][r];
            gp[4096 + idx] = acc[j * 2 + 1][r];
        }
    __syncthreads();               // all LDS reads done before overlay
    float* red = (float*)smem;
    red[tid] = csum.x; red[256 + tid] = csum.y;
    __syncthreads();
    if (tid < 32) {
        float sx = 0.f, sy = 0.f;
        for (int k = 0; k < 8; k++) { sx += red[k * 32 + tid]; sy += red[256 + k * 32 + tid]; }
        atomicAdd(&zsum[2 * tid], sx);
        atomicAdd(&zsum[2 * tid + 1], sy);
    }
}

// sum NZB partials -> G[8192]  (fully coalesced reads, plain writes)
__global__ void greduce(const float* __restrict__ Gpart, float* __restrict__ G) {
    int idx = blockIdx.x * 256 + threadIdx.x;   // 8192 total (32 blocks)
    float s = 0.f;
    for (int b = 0; b < NZB; b++) s += Gpart[(size_t)b * 8192 + idx];
    G[idx] = s;
}

// stats1 from Gram: sum_c = zsum.w_c + N b_c ; sumsq_c = w^T Ghh w + 2 w^T Ghl w + 2 b (zsum.w) + N b^2
__launch_bounds__(1024)
__global__ void bn1stat(const float* __restrict__ W1, const float* __restrict__ b1,
                        const float* __restrict__ G, const float* __restrict__ zsum,
                        int l, double* __restrict__ stats) {
    __shared__ float wsh[128 * 64];    // w[c][k]
    __shared__ float redq[1024];
    int tid = threadIdx.x;
    for (int idx = tid; idx < 8192; idx += 1024) {
        int k = idx >> 7, c = idx & 127;
        wsh[c * 64 + k] = W1[l * 8192 + idx];
    }
    __syncthreads();
    int c = tid & 127, s = tid >> 7;   // 8 i-slices per column
    const float* wc = &wsh[c * 64];
    float q = 0.f;
    for (int i = s * 8; i < s * 8 + 8; i++) {
        float dh = 0.f, dl = 0.f;
        const float* gh = &G[i * 64];
        const float* gl = &G[4096 + i * 64];
        for (int j = 0; j < 64; j++) {
            dh += gh[j] * wc[j];
            dl += gl[j] * wc[j];
        }
        q += wc[i] * (dh + 2.f * dl);
    }
    redq[tid] = q;
    __syncthreads();
    if (tid < 128) {
        float qq = 0.f;
        for (int ss = 0; ss < 8; ss++) qq += redq[ss * 128 + tid];
        const float* wcc = &wsh[tid * 64];
        float s1 = 0.f;
        for (int k = 0; k < 64; k++) s1 += zsum[k] * wcc[k];
        float bc = b1[l * 128 + tid];
        stats[tid] = (double)s1 + (double)NN * bc;
        stats[128 + tid] = (double)qq + 2.0 * bc * s1 + (double)NN * bc * bc;
    }
}

// Fused MLP: z -> GEMM1 -> bn1+relu -> GEMM2 -> t2 (+ fused t2 colstats)
__launch_bounds__(256)
__global__ void mlp_fused(const float* __restrict__ z,
                          const unsigned short* __restrict__ w1h, const unsigned short* __restrict__ w1l,
                          const float* __restrict__ b1,
                          const unsigned short* __restrict__ w2h, const unsigned short* __restrict__ w2l,
                          const float* __restrict__ b2,
                          const float* __restrict__ bn_g, const float* __restrict__ bn_b,
                          const double* __restrict__ stats1, int l,
                          float* __restrict__ t2, double* __restrict__ stats2) {
    __shared__ char smem[70656];
    unsigned short* zbh = (unsigned short*)smem;
    unsigned short* zbl = zbh + 64 * 72;
    unsigned short* wth = zbl + 64 * 72;
    unsigned short* wtl = wth + 128 * 72;
    unsigned short* rbh  = (unsigned short*)smem;
    unsigned short* rbl  = rbh + 64 * 136;
    unsigned short* w2th = rbl + 64 * 136;
    unsigned short* w2tl = w2th + 64 * 136;
    float* ca = (float*)(smem + 69632);
    float* cb = ca + 128;
    int tid = threadIdx.x;
    int base = blockIdx.x * 64;

    if (tid < 128) {
        float mean = (float)(stats1[tid] / NN);
        float var  = (float)(stats1[128 + tid] / NN) - mean * mean;
        float a = bn_g[l * 128 + tid] * rsqrtf(var + 1e-5f);
        ca[tid] = a;
        cb[tid] = bn_b[l * 128 + tid] - mean * a + a * b1[l * 128 + tid];
    }
    const unsigned short* wsh = w1h + l * 8192;
    const unsigned short* wsl = w1l + l * 8192;
    for (int it = 0; it < 4; it++) {
        int chunk = it * 256 + tid;
        int c = chunk >> 3, k0 = (chunk & 7) * 8;
        *(uint4*)&wth[c * 72 + k0] = *(const uint4*)(wsh + chunk * 8);
        *(uint4*)&wtl[c * 72 + k0] = *(const uint4*)(wsl + chunk * 8);
    }
    for (int it = 0; it < 8; it++) {
        int idx2 = (it * 256 + tid) * 2;
        int n = idx2 >> 6, col = idx2 & 63;
        int node = base + n;
        float2 v = make_float2(0.f, 0.f);
        if (node < NN) v = ((const float2*)z)[(size_t)node * 32 + (col >> 1)];
        unsigned short hx = f2bf(v.x), hy = f2bf(v.y);
        zbh[n * 72 + col] = hx;     zbh[n * 72 + col + 1] = hy;
        zbl[n * 72 + col] = f2bf(v.x - bf2f(hx));
        zbl[n * 72 + col + 1] = f2bf(v.y - bf2f(hy));
    }
    const unsigned short* w2sh = w2h + l * 8192;
    const unsigned short* w2sl = w2l + l * 8192;
    uint4 preH[4], preL[4];
    for (int it = 0; it < 4; it++) {
        preH[it] = *(const uint4*)(w2sh + (it * 256 + tid) * 8);
        preL[it] = *(const uint4*)(w2sl + (it * 256 + tid) * 8);
    }
    __syncthreads();
    int wv = tid >> 6, lane = tid & 63, m = lane & 15, qd = lane >> 4;
    short8 ah0 = *(const short8*)&zbh[(wv * 16 + m) * 72 + qd * 8];
    short8 ah1 = *(const short8*)&zbh[(wv * 16 + m) * 72 + 32 + qd * 8];
    short8 al0 = *(const short8*)&zbl[(wv * 16 + m) * 72 + qd * 8];
    short8 al1 = *(const short8*)&zbl[(wv * 16 + m) * 72 + 32 + qd * 8];
    floatx4 acc1[8];
    for (int t = 0; t < 8; t++) {
        short8 bh0 = *(const short8*)&wth[(t * 16 + m) * 72 + qd * 8];
        short8 bh1 = *(const short8*)&wth[(t * 16 + m) * 72 + 32 + qd * 8];
        short8 bl0 = *(const short8*)&wtl[(t * 16 + m) * 72 + qd * 8];
        short8 bl1 = *(const short8*)&wtl[(t * 16 + m) * 72 + 32 + qd * 8];
        floatx4 c0 = {0.f, 0.f, 0.f, 0.f};
        c0 = MFMA(ah0, bh0, c0, 0, 0, 0);
        c0 = MFMA(ah0, bl0, c0, 0, 0, 0);
        c0 = MFMA(al0, bh0, c0, 0, 0, 0);
        c0 = MFMA(ah1, bh1, c0, 0, 0, 0);
        c0 = MFMA(ah1, bl1, c0, 0, 0, 0);
        c0 = MFMA(al1, bh1, c0, 0, 0, 0);
        acc1[t] = c0;
    }
    __syncthreads();
    for (int it = 0; it < 4; it++) {
        int chunk = it * 256 + tid;
        int c = chunk >> 4, k0 = (chunk & 15) * 8;
        *(uint4*)&w2th[c * 136 + k0] = preH[it];
        *(uint4*)&w2tl[c * 136 + k0] = preL[it];
    }
    for (int t = 0; t < 8; t++) {
        int col = t * 16 + m;
        float a = ca[col], b = cb[col];
        for (int r = 0; r < 4; r++) {
            int row = wv * 16 + qd * 4 + r;
            float rv = fmaxf(a * acc1[t][r] + b, 0.f);
            unsigned short hh = f2bf(rv);
            rbh[row * 136 + col] = hh;
            rbl[row * 136 + col] = f2bf(rv - bf2f(hh));
        }
    }
    __syncthreads();
    short8 ah[4], al[4];
    for (int kh = 0; kh < 4; kh++) {
        ah[kh] = *(const short8*)&rbh[(wv * 16 + m) * 136 + kh * 32 + qd * 8];
        al[kh] = *(const short8*)&rbl[(wv * 16 + m) * 136 + kh * 32 + qd * 8];
    }
    floatx4 acc2[4];
    for (int t = 0; t < 4; t++) {
        floatx4 c0 = {0.f, 0.f, 0.f, 0.f};
        for (int kh = 0; kh < 4; kh++) {
            short8 bh = *(const short8*)&w2th[(t * 16 + m) * 136 + kh * 32 + qd * 8];
            short8 bl = *(const short8*)&w2tl[(t * 16 + m) * 136 + kh * 32 + qd * 8];
            c0 = MFMA(ah[kh], bh, c0, 0, 0, 0);
            c0 = MFMA(ah[kh], bl, c0, 0, 0, 0);
            c0 = MFMA(al[kh], bh, c0, 0, 0, 0);
        }
        acc2[t] = c0;
    }
    __syncthreads();
    float* redS = (float*)smem;
    float* redQ = redS + 1024;
    const float* bias = b2 + l * 64;
    int g = wv * 4 + qd;
    for (int t = 0; t < 4; t++) {
        int col = t * 16 + m;
        float bv = bias[col];
        float s = 0.f, ss = 0.f;
        for (int r = 0; r < 4; r++) {
            int node = base + wv * 16 + qd * 4 + r;
            if (node < NN) {
                float v = acc2[t][r] + bv;
                t2[(size_t)node * 64 + col] = v;
                s += v; ss += v * v;
            }
        }
        redS[col * 16 + g] = s;
        redQ[col * 16 + g] = ss;
    }
    __syncthreads();
    if (tid < 64) {
        float s = 0.f, ss = 0.f;
        for (int gg = 0; gg < 16; gg++) { s += redS[tid * 16 + gg]; ss += redQ[tid * 16 + gg]; }
        atomicAdd(&stats2[tid], (double)s);
        atomicAdd(&stats2[64 + tid], (double)ss);
    }
}

__global__ void bnapply_last(const float* __restrict__ t2, const float* __restrict__ bn_g,
                             const float* __restrict__ bn_b, const double* __restrict__ stats,
                             float* __restrict__ out, float* __restrict__ gsum,
                             float* __restrict__ gcnt, const int* __restrict__ batch) {
    __shared__ float ca[64], cb[64];
    int tid = threadIdx.x;
    if (tid < 64) {
        float mean = (float)(stats[tid] / NN);
        float var  = (float)(stats[64 + tid] / NN) - mean * mean;
        float a = bn_g[3 * 64 + tid] * rsqrtf(var + 1e-5f);
        ca[tid] = a;
        cb[tid] = bn_b[3 * 64 + tid] - mean * a;
    }
    __syncthreads();
    size_t base = (size_t)blockIdx.x * 4096;
    for (int it = 0; it < 16; it++) {
        size_t idx = base + it * 256 + tid;
        if (idx >= (size_t)NN * 64) return;
        int c = (int)(idx & 63);
        float v = ca[c] * t2[idx] + cb[c];
        out[idx] = v;
        int g = batch[idx >> 6];
        atomicAdd(&gsum[(size_t)g * 64 + c], v);
        if (c == 0) atomicAdd(&gcnt[g], 1.0f);
    }
}

__global__ void pool_div(const float* __restrict__ gsum, const float* __restrict__ gcnt,
                         float* __restrict__ out) {
    int id = blockIdx.x * 256 + threadIdx.x;
    int g = id >> 6;
    out[(size_t)NN * 64 + id] = gsum[id] / (gcnt[g] + 1e-9f);
}

extern "C" void kernel_launch(void* const* d_in, const int* in_sizes, int n_in,
                              void* d_out, int out_size, void* d_ws, size_t ws_size,
                              hipStream_t stream) {
    const float* atom_emb = (const float*)d_in[0];
    const float* bond_emb = (const float*)d_in[1];
    const float* eps      = (const float*)d_in[2];
    const float* W1       = (const float*)d_in[3];
    const float* b1       = (const float*)d_in[4];
    const float* bn1_g    = (const float*)d_in[5];
    const float* bn1_b    = (const float*)d_in[6];
    const float* W2       = (const float*)d_in[7];
    const float* b2       = (const float*)d_in[8];
    const float* bn2_g    = (const float*)d_in[9];
    const float* bn2_b    = (const float*)d_in[10];
    const int* x_feat     = (const int*)d_in[11];
    const int* edge_index = (const int*)d_in[12];
    const int* edge_attr  = (const int*)d_in[13];
    const int* batch      = (const int*)d_in[14];
    float* out = (float*)d_out;

    char* ws = (char*)d_ws;
    // ---- zero region (one memset) ----
    double* stats = (double*)ws;  ws += 2048 * 8;            // 8 slots x 256 doubles
    float* gsum   = (float*)ws;   ws += (size_t)NB * 64 * 4;
    float* gcnt   = (float*)ws;   ws += NB * 4;
    int* csr      = (int*)ws;     ws += (size_t)NN * 4;
    float* zsum   = (float*)ws;   ws += 4 * 64 * 4;
    size_t zbytes = (size_t)(ws - (char*)d_ws);
    // ---- rest ----
    int* bsum       = (int*)ws;       ws += 128 * 4;
    unsigned* epack = (unsigned*)ws;  ws += (size_t)NE * 4;
    float* Gpart = (float*)ws;    ws += (size_t)NZB * 8192 * 4;
    float* G     = (float*)ws;    ws += 8192 * 4;
    float* xbuf = (float*)ws;     ws += (size_t)NN * 64 * 4;   // h (l=0) / t2 (l>=1)
    float* agg  = (float*)ws;     ws += (size_t)NN * 64 * 4;
    unsigned short* w1h = (unsigned short*)ws; ws += 32768 * 2;
    unsigned short* w1l = (unsigned short*)ws; ws += 32768 * 2;
    unsigned short* w2h = (unsigned short*)ws; ws += 32768 * 2;
    unsigned short* w2l = (unsigned short*)ws; ws += 32768 * 2;

    hipMemsetAsync((void*)stats, 0, zbytes, stream);

    wcvt<<<256, 256, 0, stream>>>(W1, W2, w1h, w1l, w2h, w2l);
    deg_count<<<4883, 256, 0, stream>>>(edge_index, csr);
    scan_local<<<98, 256, 0, stream>>>(csr, bsum);
    scan_bsum<<<1, 128, 0, stream>>>(bsum);
    scan_add<<<98, 256, 0, stream>>>(csr, bsum);
    csr_fill<<<4883, 256, 0, stream>>>(edge_index, edge_attr, csr, epack);
    atom_encode<<<6250, 256, 0, stream>>>(atom_emb, x_feat, xbuf);

    for (int l = 0; l < 4; l++) {
        double* s1 = stats + (size_t)(l * 2) * 256;
        double* s2 = stats + (size_t)(l * 2 + 1) * 256;
        if (l == 0) {
            gather_k<false><<<6250, 256, 0, stream>>>(xbuf, bond_emb, eps, csr, epack, l,
                                                      nullptr, nullptr, nullptr, agg);
        } else {
            double* sp = stats + (size_t)((l - 1) * 2 + 1) * 256;
            gather_k<true><<<6250, 256, 0, stream>>>(xbuf, bond_emb, eps, csr, epack, l,
                                                     sp, bn2_g, bn2_b, agg);
        }
        zstat<<<NZB, 256, 0, stream>>>(agg, Gpart, zsum + l * 64);
        greduce<<<32, 256, 0, stream>>>(Gpart, G);
        bn1stat<<<1, 1024, 0, stream>>>(W1, b1, G, zsum + l * 64, l, s1);
        mlp_fused<<<1563, 256, 0, stream>>>(agg, w1h, w1l, b1, w2h, w2l, b2,
                                            bn1_g, bn1_b, s1, l, xbuf, s2);
    }
    bnapply_last<<<1563, 256, 0, stream>>>(xbuf, bn2_g, bn2_b,
                                           stats + (size_t)(3 * 2 + 1) * 256,
                                           out, gsum, gcnt, batch);
    pool_div<<<512, 256, 0, stream>>>(gsum, gcnt, out);
}

// Round 9
// 1041.114 us; speedup vs baseline: 1.3476x; 1.2726x over previous
//
#include <hip/hip_runtime.h>

#define NN 100000
#define NE 1250000
#define NB 2048
#define NZB 391    // zstat blocks (391*256 = 100096 >= NN)

typedef __attribute__((ext_vector_type(8))) short short8;
typedef __attribute__((ext_vector_type(4))) float floatx4;

__device__ inline unsigned short f2bf(float f) {
    unsigned u = __float_as_uint(f);
    u = u + 0x7fffu + ((u >> 16) & 1u);   // RNE
    return (unsigned short)(u >> 16);
}
__device__ inline float bf2f(unsigned short h) {
    return __uint_as_float(((unsigned)h) << 16);
}

// h[n][d] = sum_f atom_emb[f][x_feat[n][f]][d]
__global__ void atom_encode(const float* __restrict__ atom_emb,
                            const int* __restrict__ x_feat,
                            float* __restrict__ h) {
    int id = blockIdx.x * 256 + threadIdx.x;   // N*16 exact
    int n = id >> 4, q = id & 15;
    floatx4 acc = {0.f, 0.f, 0.f, 0.f};
    for (int f = 0; f < 9; f++) {
        int v = x_feat[n * 9 + f];
        const floatx4* p = (const floatx4*)(atom_emb + (size_t)(f * 128 + v) * 64);
        acc += p[q];
    }
    ((floatx4*)h)[(size_t)n * 16 + q] = acc;
}

// ---- CSR build ----
__global__ void deg_count(const int* __restrict__ ei, int* __restrict__ csr) {
    int e = blockIdx.x * 256 + threadIdx.x;
    if (e < NE) atomicAdd(&csr[ei[NE + e]], 1);
}

__global__ void scan_local(int* __restrict__ csr, int* __restrict__ bsum) {
    __shared__ int ls[256];
    int tid = threadIdx.x;
    int base = blockIdx.x * 1024 + tid * 4;
    int4 v = make_int4(0, 0, 0, 0);
    if (base + 3 < NN) {
        v = *(const int4*)(csr + base);
    } else {
        if (base + 0 < NN) v.x = csr[base + 0];
        if (base + 1 < NN) v.y = csr[base + 1];
        if (base + 2 < NN) v.z = csr[base + 2];
        if (base + 3 < NN) v.w = csr[base + 3];
    }
    int s = v.x + v.y + v.z + v.w;
    ls[tid] = s;
    __syncthreads();
    for (int d = 1; d < 256; d <<= 1) {
        int t = (tid >= d) ? ls[tid - d] : 0;
        __syncthreads();
        ls[tid] += t;
        __syncthreads();
    }
    if (tid == 255) bsum[blockIdx.x] = ls[255];
    int e0 = tid ? ls[tid - 1] : 0;
    int4 w;
    w.x = e0; w.y = e0 + v.x; w.z = w.y + v.y; w.w = w.z + v.z;
    if (base + 3 < NN) {
        *(int4*)(csr + base) = w;
    } else {
        if (base + 0 < NN) csr[base + 0] = w.x;
        if (base + 1 < NN) csr[base + 1] = w.y;
        if (base + 2 < NN) csr[base + 2] = w.z;
        if (base + 3 < NN) csr[base + 3] = w.w;
    }
}

__global__ void scan_bsum(int* __restrict__ bsum) {
    __shared__ int ls[128];
    int tid = threadIdx.x;
    int v = (tid < 98) ? bsum[tid] : 0;
    ls[tid] = v;
    __syncthreads();
    for (int d = 1; d < 128; d <<= 1) {
        int t = (tid >= d) ? ls[tid - d] : 0;
        __syncthreads();
        ls[tid] += t;
        __syncthreads();
    }
    if (tid < 98) bsum[tid] = tid ? ls[tid - 1] : 0;
}

__global__ void scan_add(int* __restrict__ csr, const int* __restrict__ bsum) {
    int off = bsum[blockIdx.x];
    int base = blockIdx.x * 1024 + threadIdx.x * 4;
    if (base + 3 < NN) {
        int4 v = *(const int4*)(csr + base);
        v.x += off; v.y += off; v.z += off; v.w += off;
        *(int4*)(csr + base) = v;
    } else {
        for (int i = 0; i < 4; i++)
            if (base + i < NN) csr[base + i] += off;
    }
}

// packed record: src (17b) | a0 (3b) | a1 (3b) | a2 (3b)
__global__ void csr_fill(const int* __restrict__ ei, const int* __restrict__ ea,
                         int* __restrict__ csr, unsigned* __restrict__ epack) {
    int e = blockIdx.x * 256 + threadIdx.x;
    if (e >= NE) return;
    int dst = ei[NE + e];
    int pos = atomicAdd(&csr[dst], 1);
    unsigned at = (unsigned)(ea[e * 3] | (ea[e * 3 + 1] << 3) | (ea[e * 3 + 2] << 6));
    epack[pos] = (unsigned)ei[e] | (at << 17);
}

// agg[n] = (1+eps)*h[n] + sum_{e: dst==n} relu(h[src_e] + bond(e))
template <bool HASBN>
__global__ void gather_k(const float* __restrict__ x, const float* __restrict__ bond_emb,
                         const float* __restrict__ eps, const int* __restrict__ csr,
                         const unsigned* __restrict__ epack, int l,
                         const double* __restrict__ stats, const float* __restrict__ bn_g,
                         const float* __restrict__ bn_b, float* __restrict__ agg) {
    __shared__ float be[24 * 64];
    __shared__ float ca[64], cb[64];
    int tid = threadIdx.x;
    const float* bsrc = bond_emb + (size_t)l * 1536;
    for (int i = tid; i < 1536; i += 256) be[i] = bsrc[i];
    if (tid < 64) {
        if (HASBN) {
            float mean = (float)(stats[tid] / NN);
            float var  = (float)(stats[64 + tid] / NN) - mean * mean;
            float a = bn_g[(l - 1) * 64 + tid] * rsqrtf(var + 1e-5f);
            ca[tid] = a;
            cb[tid] = bn_b[(l - 1) * 64 + tid] - mean * a;
        } else {
            ca[tid] = 1.f; cb[tid] = 0.f;
        }
    }
    __syncthreads();
    int id = blockIdx.x * 256 + tid;           // NN*16 exact
    int n = id >> 4, q = id & 15;
    float s = 1.0f + eps[l];
    floatx4 cav = *(const floatx4*)&ca[q * 4];
    floatx4 cbv = *(const floatx4*)&cb[q * 4];
    floatx4 xv = ((const floatx4*)x)[(size_t)n * 16 + q];
    if (HASBN) {
        xv[0] = fmaxf(cav[0] * xv[0] + cbv[0], 0.f);
        xv[1] = fmaxf(cav[1] * xv[1] + cbv[1], 0.f);
        xv[2] = fmaxf(cav[2] * xv[2] + cbv[2], 0.f);
        xv[3] = fmaxf(cav[3] * xv[3] + cbv[3], 0.f);
    }
    floatx4 acc = xv * s;
    int k0 = n ? csr[n - 1] : 0;
    int k1 = csr[n];
    const floatx4* beq = (const floatx4*)be;
    unsigned rec = (k0 < k1) ? epack[k0] : 0u;
    for (int k = k0; k < k1; k++) {
        unsigned cur = rec;
        if (k + 1 < k1) rec = epack[k + 1];
        int src = (int)(cur & 0x1FFFFu);
        floatx4 m = ((const floatx4*)x)[(size_t)src * 16 + q];
        if (HASBN) {
            m[0] = fmaxf(cav[0] * m[0] + cbv[0], 0.f);
            m[1] = fmaxf(cav[1] * m[1] + cbv[1], 0.f);
            m[2] = fmaxf(cav[2] * m[2] + cbv[2], 0.f);
            m[3] = fmaxf(cav[3] * m[3] + cbv[3], 0.f);
        }
        m += beq[((cur >> 17) & 7u) * 16 + q];
        m += beq[(8 + ((cur >> 20) & 7u)) * 16 + q];
        m += beq[(16 + ((cur >> 23) & 7u)) * 16 + q];
        acc[0] += fmaxf(m[0], 0.f);
        acc[1] += fmaxf(m[1], 0.f);
        acc[2] += fmaxf(m[2], 0.f);
        acc[3] += fmaxf(m[3], 0.f);
    }
    ((floatx4*)agg)[(size_t)n * 16 + q] = acc;
}

// weights -> split bf16 transposed
__global__ void wcvt(const float* __restrict__ W1, const float* __restrict__ W2,
                     unsigned short* __restrict__ w1h, unsigned short* __restrict__ w1l,
                     unsigned short* __restrict__ w2h, unsigned short* __restrict__ w2l) {
    int id = blockIdx.x * 256 + threadIdx.x;
    if (id < 32768) {
        int l = id >> 13, rem = id & 8191, c = rem >> 6, k = rem & 63;
        float w = W1[l * 8192 + k * 128 + c];
        unsigned short hh = f2bf(w);
        w1h[id] = hh; w1l[id] = f2bf(w - bf2f(hh));
    } else {
        int id2 = id - 32768;
        int l = id2 >> 13, rem = id2 & 8191, c = rem >> 7, k = rem & 127;
        float w = W2[l * 8192 + k * 64 + c];
        unsigned short hh = f2bf(w);
        w2h[id2] = hh; w2l[id2] = f2bf(w - bf2f(hh));
    }
}

#define MFMA __builtin_amdgcn_mfma_f32_16x16x32_bf16

// Gram pass: per-block partials of G_hh = Zh^T Zh, G_hl = Zh^T Zl over 256 nodes.
#define ZS 264   // LDS stride in shorts (256 + 8 pad)
__launch_bounds__(256)
__global__ void zstat(const float* __restrict__ z, float* __restrict__ Gpart,
                      float* __restrict__ zsum) {
    __shared__ char smem[67584];
    unsigned short* zh = (unsigned short*)smem;            // 64 x ZS
    unsigned short* zl = zh + 64 * ZS;
    int tid = threadIdx.x;
    int c2 = tid & 31;            // col-pair id
    int nof = tid >> 5;           // node sub-offset 0..7
    int wv = tid >> 6, lane = tid & 63, m = lane & 15, qd = lane >> 4;
    float2 csum = make_float2(0.f, 0.f);
    floatx4 acc[8];               // 4 j-tiles x {hh, hl}
    for (int t = 0; t < 8; t++) acc[t] = (floatx4){0.f, 0.f, 0.f, 0.f};
    int base = blockIdx.x * 256;
    for (int it = 0; it < 32; it++) {
        int n = it * 8 + nof;
        int node = base + n;
        float2 v = make_float2(0.f, 0.f);
        if (node < NN) v = ((const float2*)z)[(size_t)node * 32 + c2];
        csum.x += v.x; csum.y += v.y;
        unsigned short hx = f2bf(v.x), hy = f2bf(v.y);
        zh[(2 * c2) * ZS + n] = hx;
        zh[(2 * c2 + 1) * ZS + n] = hy;
        zl[(2 * c2) * ZS + n] = f2bf(v.x - bf2f(hx));
        zl[(2 * c2 + 1) * ZS + n] = f2bf(v.y - bf2f(hy));
    }
    __syncthreads();
    for (int kc = 0; kc < 8; kc++) {
        short8 ah = *(const short8*)&zh[(wv * 16 + m) * ZS + kc * 32 + qd * 8];
        for (int j = 0; j < 4; j++) {
            short8 bh = *(const short8*)&zh[(j * 16 + m) * ZS + kc * 32 + qd * 8];
            short8 bl = *(const short8*)&zl[(j * 16 + m) * ZS + kc * 32 + qd * 8];
            acc[j * 2]     = MFMA(ah, bh, acc[j * 2], 0, 0, 0);
            acc[j * 2 + 1] = MFMA(ah, bl, acc[j * 2 + 1], 0, 0, 0);
        }
    }
    float* gp = Gpart + (size_t)blockIdx.x * 8192;
    for (int j = 0; j < 4; j++)
        for (int r = 0; r < 4; r++) {
            int idx = (wv * 16 + qd * 4 + r) * 64 + j * 16 + m;
            gp[idx] = acc[j * 2][r];
            gp[4096 + idx] = acc[j * 2 + 1][r];
        }
    __syncthreads();               // all LDS reads done before overlay
    float* red = (float*)smem;
    red[tid] = csum.x; red[256 + tid] = csum.y;
    __syncthreads();
    if (tid < 32) {
        float sx = 0.f, sy = 0.f;
        for (int k = 0; k < 8; k++) { sx += red[k * 32 + tid]; sy += red[256 + k * 32 + tid]; }
        atomicAdd(&zsum[2 * tid], sx);
        atomicAdd(&zsum[2 * tid + 1], sy);
    }
}

// sum NZB partials -> G[8192] (per-layer, zeroed). grid (32, 4): y = partial-range.
__global__ void greduce(const float* __restrict__ Gpart, float* __restrict__ G) {
    int idx = blockIdx.x * 256 + threadIdx.x;   // 8192 outputs
    int b0 = blockIdx.y * 98;
    int b1 = b0 + 98; if (b1 > NZB) b1 = NZB;
    float s = 0.f;
    for (int b = b0; b < b1; b++) s += Gpart[(size_t)b * 8192 + idx];
    atomicAdd(&G[idx], s);
}

// stats1 from Gram, one block per channel c (128 blocks x 256 threads):
// sum_c = zsum.w_c + N b_c ; sumsq_c = w^T (Ghh + 2 Ghl) w + 2 b (zsum.w) + N b^2
__launch_bounds__(256)
__global__ void bn1stat(const float* __restrict__ W1, const float* __restrict__ b1,
                        const float* __restrict__ G, const float* __restrict__ zsum,
                        int l, double* __restrict__ stats) {
    __shared__ float wc[64];
    __shared__ float red[256];
    int c = blockIdx.x;
    int tid = threadIdx.x;
    if (tid < 64) wc[tid] = W1[l * 8192 + tid * 128 + c];   // W1[l][k][c]
    __syncthreads();
    float q = 0.f;
    for (int p = 0; p < 16; p++) {
        int idx = p * 256 + tid;           // coalesced over G
        int i = idx >> 6, j = idx & 63;
        q += wc[i] * wc[j] * (G[idx] + 2.f * G[4096 + idx]);
    }
    red[tid] = q;
    __syncthreads();
    for (int d = 128; d > 0; d >>= 1) {
        if (tid < d) red[tid] += red[tid + d];
        __syncthreads();
    }
    if (tid == 0) {
        float s1 = 0.f;
        for (int k = 0; k < 64; k++) s1 += zsum[k] * wc[k];
        float bc = b1[l * 128 + c];
        stats[c] = (double)s1 + (double)NN * bc;
        stats[128 + c] = (double)red[0] + 2.0 * bc * s1 + (double)NN * bc * bc;
    }
}

// Fused MLP: z -> GEMM1 -> bn1+relu -> GEMM2 -> t2 (+ fused t2 colstats)
__launch_bounds__(256)
__global__ void mlp_fused(const float* __restrict__ z,
                          const unsigned short* __restrict__ w1h, const unsigned short* __restrict__ w1l,
                          const float* __restrict__ b1,
                          const unsigned short* __restrict__ w2h, const unsigned short* __restrict__ w2l,
                          const float* __restrict__ b2,
                          const float* __restrict__ bn_g, const float* __restrict__ bn_b,
                          const double* __restrict__ stats1, int l,
                          float* __restrict__ t2, double* __restrict__ stats2) {
    __shared__ char smem[70656];
    unsigned short* zbh = (unsigned short*)smem;
    unsigned short* zbl = zbh + 64 * 72;
    unsigned short* wth = zbl + 64 * 72;
    unsigned short* wtl = wth + 128 * 72;
    unsigned short* rbh  = (unsigned short*)smem;
    unsigned short* rbl  = rbh + 64 * 136;
    unsigned short* w2th = rbl + 64 * 136;
    unsigned short* w2tl = w2th + 64 * 136;
    float* ca = (float*)(smem + 69632);
    float* cb = ca + 128;
    int tid = threadIdx.x;
    int base = blockIdx.x * 64;

    if (tid < 128) {
        float mean = (float)(stats1[tid] / NN);
        float var  = (float)(stats1[128 + tid] / NN) - mean * mean;
        float a = bn_g[l * 128 + tid] * rsqrtf(var + 1e-5f);
        ca[tid] = a;
        cb[tid] = bn_b[l * 128 + tid] - mean * a + a * b1[l * 128 + tid];
    }
    const unsigned short* wsh = w1h + l * 8192;
    const unsigned short* wsl = w1l + l * 8192;
    for (int it = 0; it < 4; it++) {
        int chunk = it * 256 + tid;
        int c = chunk >> 3, k0 = (chunk & 7) * 8;
        *(uint4*)&wth[c * 72 + k0] = *(const uint4*)(wsh + chunk * 8);
        *(uint4*)&wtl[c * 72 + k0] = *(const uint4*)(wsl + chunk * 8);
    }
    for (int it = 0; it < 8; it++) {
        int idx2 = (it * 256 + tid) * 2;
        int n = idx2 >> 6, col = idx2 & 63;
        int node = base + n;
        float2 v = make_float2(0.f, 0.f);
        if (node < NN) v = ((const float2*)z)[(size_t)node * 32 + (col >> 1)];
        unsigned short hx = f2bf(v.x), hy = f2bf(v.y);
        zbh[n * 72 + col] = hx;     zbh[n * 72 + col + 1] = hy;
        zbl[n * 72 + col] = f2bf(v.x - bf2f(hx));
        zbl[n * 72 + col + 1] = f2bf(v.y - bf2f(hy));
    }
    const unsigned short* w2sh = w2h + l * 8192;
    const unsigned short* w2sl = w2l + l * 8192;
    uint4 preH[4], preL[4];
    for (int it = 0; it < 4; it++) {
        preH[it] = *(const uint4*)(w2sh + (it * 256 + tid) * 8);
        preL[it] = *(const uint4*)(w2sl + (it * 256 + tid) * 8);
    }
    __syncthreads();
    int wv = tid >> 6, lane = tid & 63, m = lane & 15, qd = lane >> 4;
    short8 ah0 = *(const short8*)&zbh[(wv * 16 + m) * 72 + qd * 8];
    short8 ah1 = *(const short8*)&zbh[(wv * 16 + m) * 72 + 32 + qd * 8];
    short8 al0 = *(const short8*)&zbl[(wv * 16 + m) * 72 + qd * 8];
    short8 al1 = *(const short8*)&zbl[(wv * 16 + m) * 72 + 32 + qd * 8];
    floatx4 acc1[8];
    for (int t = 0; t < 8; t++) {
        short8 bh0 = *(const short8*)&wth[(t * 16 + m) * 72 + qd * 8];
        short8 bh1 = *(const short8*)&wth[(t * 16 + m) * 72 + 32 + qd * 8];
        short8 bl0 = *(const short8*)&wtl[(t * 16 + m) * 72 + qd * 8];
        short8 bl1 = *(const short8*)&wtl[(t * 16 + m) * 72 + 32 + qd * 8];
        floatx4 c0 = {0.f, 0.f, 0.f, 0.f};
        c0 = MFMA(ah0, bh0, c0, 0, 0, 0);
        c0 = MFMA(ah0, bl0, c0, 0, 0, 0);
        c0 = MFMA(al0, bh0, c0, 0, 0, 0);
        c0 = MFMA(ah1, bh1, c0, 0, 0, 0);
        c0 = MFMA(ah1, bl1, c0, 0, 0, 0);
        c0 = MFMA(al1, bh1, c0, 0, 0, 0);
        acc1[t] = c0;
    }
    __syncthreads();
    for (int it = 0; it < 4; it++) {
        int chunk = it * 256 + tid;
        int c = chunk >> 4, k0 = (chunk & 15) * 8;
        *(uint4*)&w2th[c * 136 + k0] = preH[it];
        *(uint4*)&w2tl[c * 136 + k0] = preL[it];
    }
    for (int t = 0; t < 8; t++) {
        int col = t * 16 + m;
        float a = ca[col], b = cb[col];
        for (int r = 0; r < 4; r++) {
            int row = wv * 16 + qd * 4 + r;
            float rv = fmaxf(a * acc1[t][r] + b, 0.f);
            unsigned short hh = f2bf(rv);
            rbh[row * 136 + col] = hh;
            rbl[row * 136 + col] = f2bf(rv - bf2f(hh));
        }
    }
    __syncthreads();
    short8 ah[4], al[4];
    for (int kh = 0; kh < 4; kh++) {
        ah[kh] = *(const short8*)&rbh[(wv * 16 + m) * 136 + kh * 32 + qd * 8];
        al[kh] = *(const short8*)&rbl[(wv * 16 + m) * 136 + kh * 32 + qd * 8];
    }
    floatx4 acc2[4];
    for (int t = 0; t < 4; t++) {
        floatx4 c0 = {0.f, 0.f, 0.f, 0.f};
        for (int kh = 0; kh < 4; kh++) {
            short8 bh = *(const short8*)&w2th[(t * 16 + m) * 136 + kh * 32 + qd * 8];
            short8 bl = *(const short8*)&w2tl[(t * 16 + m) * 136 + kh * 32 + qd * 8];
            c0 = MFMA(ah[kh], bh, c0, 0, 0, 0);
            c0 = MFMA(ah[kh], bl, c0, 0, 0, 0);
            c0 = MFMA(al[kh], bh, c0, 0, 0, 0);
        }
        acc2[t] = c0;
    }
    __syncthreads();
    float* redS = (float*)smem;
    float* redQ = redS + 1024;
    const float* bias = b2 + l * 64;
    int g = wv * 4 + qd;
    for (int t = 0; t < 4; t++) {
        int col = t * 16 + m;
        float bv = bias[col];
        float s = 0.f, ss = 0.f;
        for (int r = 0; r < 4; r++) {
            int node = base + wv * 16 + qd * 4 + r;
            if (node < NN) {
                float v = acc2[t][r] + bv;
                t2[(size_t)node * 64 + col] = v;
                s += v; ss += v * v;
            }
        }
        redS[col * 16 + g] = s;
        redQ[col * 16 + g] = ss;
    }
    __syncthreads();
    if (tid < 64) {
        float s = 0.f, ss = 0.f;
        for (int gg = 0; gg < 16; gg++) { s += redS[tid * 16 + gg]; ss += redQ[tid * 16 + gg]; }
        atomicAdd(&stats2[tid], (double)s);
        atomicAdd(&stats2[64 + tid], (double)ss);
    }
}

__global__ void bnapply_last(const float* __restrict__ t2, const float* __restrict__ bn_g,
                             const float* __restrict__ bn_b, const double* __restrict__ stats,
                             float* __restrict__ out, float* __restrict__ gsum,
                             float* __restrict__ gcnt, const int* __restrict__ batch) {
    __shared__ float ca[64], cb[64];
    int tid = threadIdx.x;
    if (tid < 64) {
        float mean = (float)(stats[tid] / NN);
        float var  = (float)(stats[64 + tid] / NN) - mean * mean;
        float a = bn_g[3 * 64 + tid] * rsqrtf(var + 1e-5f);
        ca[tid] = a;
        cb[tid] = bn_b[3 * 64 + tid] - mean * a;
    }
    __syncthreads();
    size_t base = (size_t)blockIdx.x * 4096;
    for (int it = 0; it < 16; it++) {
        size_t idx = base + it * 256 + tid;
        if (idx >= (size_t)NN * 64) return;
        int c = (int)(idx & 63);
        float v = ca[c] * t2[idx] + cb[c];
        out[idx] = v;
        int g = batch[idx >> 6];
        atomicAdd(&gsum[(size_t)g * 64 + c], v);
        if (c == 0) atomicAdd(&gcnt[g], 1.0f);
    }
}

__global__ void pool_div(const float* __restrict__ gsum, const float* __restrict__ gcnt,
                         float* __restrict__ out) {
    int id = blockIdx.x * 256 + threadIdx.x;
    int g = id >> 6;
    out[(size_t)NN * 64 + id] = gsum[id] / (gcnt[g] + 1e-9f);
}

extern "C" void kernel_launch(void* const* d_in, const int* in_sizes, int n_in,
                              void* d_out, int out_size, void* d_ws, size_t ws_size,
                              hipStream_t stream) {
    const float* atom_emb = (const float*)d_in[0];
    const float* bond_emb = (const float*)d_in[1];
    const float* eps      = (const float*)d_in[2];
    const float* W1       = (const float*)d_in[3];
    const float* b1       = (const float*)d_in[4];
    const float* bn1_g    = (const float*)d_in[5];
    const float* bn1_b    = (const float*)d_in[6];
    const float* W2       = (const float*)d_in[7];
    const float* b2       = (const float*)d_in[8];
    const float* bn2_g    = (const float*)d_in[9];
    const float* bn2_b    = (const float*)d_in[10];
    const int* x_feat     = (const int*)d_in[11];
    const int* edge_index = (const int*)d_in[12];
    const int* edge_attr  = (const int*)d_in[13];
    const int* batch      = (const int*)d_in[14];
    float* out = (float*)d_out;

    char* ws = (char*)d_ws;
    // ---- zero region (one memset) ----
    double* stats = (double*)ws;  ws += 2048 * 8;            // 8 slots x 256 doubles
    float* gsum   = (float*)ws;   ws += (size_t)NB * 64 * 4;
    float* gcnt   = (float*)ws;   ws += NB * 4;
    int* csr      = (int*)ws;     ws += (size_t)NN * 4;
    float* zsum   = (float*)ws;   ws += 4 * 64 * 4;
    float* G      = (float*)ws;   ws += (size_t)4 * 8192 * 4;  // per-layer [Ghh|Ghl]
    size_t zbytes = (size_t)(ws - (char*)d_ws);
    // ---- rest ----
    int* bsum       = (int*)ws;       ws += 128 * 4;
    unsigned* epack = (unsigned*)ws;  ws += (size_t)NE * 4;
    float* Gpart = (float*)ws;    ws += (size_t)NZB * 8192 * 4;
    float* xbuf = (float*)ws;     ws += (size_t)NN * 64 * 4;   // h (l=0) / t2 (l>=1)
    float* agg  = (float*)ws;     ws += (size_t)NN * 64 * 4;
    unsigned short* w1h = (unsigned short*)ws; ws += 32768 * 2;
    unsigned short* w1l = (unsigned short*)ws; ws += 32768 * 2;
    unsigned short* w2h = (unsigned short*)ws; ws += 32768 * 2;
    unsigned short* w2l = (unsigned short*)ws; ws += 32768 * 2;

    hipMemsetAsync((void*)stats, 0, zbytes, stream);

    wcvt<<<256, 256, 0, stream>>>(W1, W2, w1h, w1l, w2h, w2l);
    deg_count<<<4883, 256, 0, stream>>>(edge_index, csr);
    scan_local<<<98, 256, 0, stream>>>(csr, bsum);
    scan_bsum<<<1, 128, 0, stream>>>(bsum);
    scan_add<<<98, 256, 0, stream>>>(csr, bsum);
    csr_fill<<<4883, 256, 0, stream>>>(edge_index, edge_attr, csr, epack);
    atom_encode<<<6250, 256, 0, stream>>>(atom_emb, x_feat, xbuf);

    for (int l = 0; l < 4; l++) {
        double* s1 = stats + (size_t)(l * 2) * 256;
        double* s2 = stats + (size_t)(l * 2 + 1) * 256;
        if (l == 0) {
            gather_k<false><<<6250, 256, 0, stream>>>(xbuf, bond_emb, eps, csr, epack, l,
                                                      nullptr, nullptr, nullptr, agg);
        } else {
            double* sp = stats + (size_t)((l - 1) * 2 + 1) * 256;
            gather_k<true><<<6250, 256, 0, stream>>>(xbuf, bond_emb, eps, csr, epack, l,
                                                     sp, bn2_g, bn2_b, agg);
        }
        float* Gl = G + (size_t)l * 8192;
        zstat<<<NZB, 256, 0, stream>>>(agg, Gpart, zsum + l * 64);
        greduce<<<dim3(32, 4), 256, 0, stream>>>(Gpart, Gl);
        bn1stat<<<128, 256, 0, stream>>>(W1, b1, Gl, zsum + l * 64, l, s1);
        mlp_fused<<<1563, 256, 0, stream>>>(agg, w1h, w1l, b1, w2h, w2l, b2,
                                            bn1_g, bn1_b, s1, l, xbuf, s2);
    }
    bnapply_last<<<1563, 256, 0, stream>>>(xbuf, bn2_g, bn2_b,
                                           stats + (size_t)(3 * 2 + 1) * 256,
                                           out, gsum, gcnt, batch);
    pool_div<<<512, 256, 0, stream>>>(gsum, gcnt, out);
}

// Round 10
// 941.264 us; speedup vs baseline: 1.4906x; 1.1061x over previous
//
#include <hip/hip_runtime.h>

#define NN 100000
#define NE 1250000
#define NB 2048
#define NZB 391    // zstat blocks (391*256 = 100096 >= NN)

typedef __attribute__((ext_vector_type(8))) short short8;
typedef __attribute__((ext_vector_type(4))) float floatx4;

__device__ inline unsigned short f2bf(float f) {
    unsigned u = __float_as_uint(f);
    u = u + 0x7fffu + ((u >> 16) & 1u);   // RNE
    return (unsigned short)(u >> 16);
}
__device__ inline float bf2f(unsigned short h) {
    return __uint_as_float(((unsigned)h) << 16);
}

// h[n][d] = sum_f atom_emb[f][x_feat[n][f]][d]  (fp32 + bf16 mirror)
__global__ void atom_encode(const float* __restrict__ atom_emb,
                            const int* __restrict__ x_feat,
                            float* __restrict__ h, unsigned short* __restrict__ h16) {
    int id = blockIdx.x * 256 + threadIdx.x;   // N*16 exact
    int n = id >> 4, q = id & 15;
    floatx4 acc = {0.f, 0.f, 0.f, 0.f};
    for (int f = 0; f < 9; f++) {
        int v = x_feat[n * 9 + f];
        const floatx4* p = (const floatx4*)(atom_emb + (size_t)(f * 128 + v) * 64);
        acc += p[q];
    }
    ((floatx4*)h)[(size_t)n * 16 + q] = acc;
    ushort4 hv;
    hv.x = f2bf(acc[0]); hv.y = f2bf(acc[1]); hv.z = f2bf(acc[2]); hv.w = f2bf(acc[3]);
    ((ushort4*)h16)[(size_t)n * 16 + q] = hv;
}

// ---- CSR build ----
__global__ void deg_count(const int* __restrict__ ei, int* __restrict__ csr) {
    int e = blockIdx.x * 256 + threadIdx.x;
    if (e < NE) atomicAdd(&csr[ei[NE + e]], 1);
}

__global__ void scan_local(int* __restrict__ csr, int* __restrict__ bsum) {
    __shared__ int ls[256];
    int tid = threadIdx.x;
    int base = blockIdx.x * 1024 + tid * 4;
    int4 v = make_int4(0, 0, 0, 0);
    if (base + 3 < NN) {
        v = *(const int4*)(csr + base);
    } else {
        if (base + 0 < NN) v.x = csr[base + 0];
        if (base + 1 < NN) v.y = csr[base + 1];
        if (base + 2 < NN) v.z = csr[base + 2];
        if (base + 3 < NN) v.w = csr[base + 3];
    }
    int s = v.x + v.y + v.z + v.w;
    ls[tid] = s;
    __syncthreads();
    for (int d = 1; d < 256; d <<= 1) {
        int t = (tid >= d) ? ls[tid - d] : 0;
        __syncthreads();
        ls[tid] += t;
        __syncthreads();
    }
    if (tid == 255) bsum[blockIdx.x] = ls[255];
    int e0 = tid ? ls[tid - 1] : 0;
    int4 w;
    w.x = e0; w.y = e0 + v.x; w.z = w.y + v.y; w.w = w.z + v.z;
    if (base + 3 < NN) {
        *(int4*)(csr + base) = w;
    } else {
        if (base + 0 < NN) csr[base + 0] = w.x;
        if (base + 1 < NN) csr[base + 1] = w.y;
        if (base + 2 < NN) csr[base + 2] = w.z;
        if (base + 3 < NN) csr[base + 3] = w.w;
    }
}

__global__ void scan_bsum(int* __restrict__ bsum) {
    __shared__ int ls[128];
    int tid = threadIdx.x;
    int v = (tid < 98) ? bsum[tid] : 0;
    ls[tid] = v;
    __syncthreads();
    for (int d = 1; d < 128; d <<= 1) {
        int t = (tid >= d) ? ls[tid - d] : 0;
        __syncthreads();
        ls[tid] += t;
        __syncthreads();
    }
    if (tid < 98) bsum[tid] = tid ? ls[tid - 1] : 0;
}

__global__ void scan_add(int* __restrict__ csr, const int* __restrict__ bsum) {
    int off = bsum[blockIdx.x];
    int base = blockIdx.x * 1024 + threadIdx.x * 4;
    if (base + 3 < NN) {
        int4 v = *(const int4*)(csr + base);
        v.x += off; v.y += off; v.z += off; v.w += off;
        *(int4*)(csr + base) = v;
    } else {
        for (int i = 0; i < 4; i++)
            if (base + i < NN) csr[base + i] += off;
    }
}

// packed record: src (17b) | a0 (3b) | a1 (3b) | a2 (3b)
__global__ void csr_fill(const int* __restrict__ ei, const int* __restrict__ ea,
                         int* __restrict__ csr, unsigned* __restrict__ epack) {
    int e = blockIdx.x * 256 + threadIdx.x;
    if (e >= NE) return;
    int dst = ei[NE + e];
    int pos = atomicAdd(&csr[dst], 1);
    unsigned at = (unsigned)(ea[e * 3] | (ea[e * 3 + 1] << 3) | (ea[e * 3 + 2] << 6));
    epack[pos] = (unsigned)ei[e] | (at << 17);
}

// agg[n] = (1+eps)*h[n] + sum_{e: dst==n} relu(h[src_e] + bond(e))
// self-term from fp32 x; neighbor gathers from bf16 mirror x16 (halves random-read bytes)
template <bool HASBN>
__global__ void gather_k(const float* __restrict__ x, const unsigned short* __restrict__ x16,
                         const float* __restrict__ bond_emb,
                         const float* __restrict__ eps, const int* __restrict__ csr,
                         const unsigned* __restrict__ epack, int l,
                         const double* __restrict__ stats, const float* __restrict__ bn_g,
                         const float* __restrict__ bn_b, float* __restrict__ agg) {
    __shared__ float be[24 * 64];
    __shared__ float ca[64], cb[64];
    int tid = threadIdx.x;
    const float* bsrc = bond_emb + (size_t)l * 1536;
    for (int i = tid; i < 1536; i += 256) be[i] = bsrc[i];
    if (tid < 64) {
        if (HASBN) {
            float mean = (float)(stats[tid] / NN);
            float var  = (float)(stats[64 + tid] / NN) - mean * mean;
            float a = bn_g[(l - 1) * 64 + tid] * rsqrtf(var + 1e-5f);
            ca[tid] = a;
            cb[tid] = bn_b[(l - 1) * 64 + tid] - mean * a;
        } else {
            ca[tid] = 1.f; cb[tid] = 0.f;
        }
    }
    __syncthreads();
    int id = blockIdx.x * 256 + tid;           // NN*16 exact
    int n = id >> 4, q = id & 15;
    float s = 1.0f + eps[l];
    floatx4 cav = *(const floatx4*)&ca[q * 4];
    floatx4 cbv = *(const floatx4*)&cb[q * 4];
    floatx4 xv = ((const floatx4*)x)[(size_t)n * 16 + q];
    if (HASBN) {
        xv[0] = fmaxf(cav[0] * xv[0] + cbv[0], 0.f);
        xv[1] = fmaxf(cav[1] * xv[1] + cbv[1], 0.f);
        xv[2] = fmaxf(cav[2] * xv[2] + cbv[2], 0.f);
        xv[3] = fmaxf(cav[3] * xv[3] + cbv[3], 0.f);
    }
    floatx4 acc = xv * s;
    int k0 = n ? csr[n - 1] : 0;
    int k1 = csr[n];
    const floatx4* beq = (const floatx4*)be;
    unsigned rec = (k0 < k1) ? epack[k0] : 0u;
    for (int k = k0; k < k1; k++) {
        unsigned cur = rec;
        if (k + 1 < k1) rec = epack[k + 1];
        int src = (int)(cur & 0x1FFFFu);
        ushort4 mh = ((const ushort4*)x16)[(size_t)src * 16 + q];
        floatx4 m = {bf2f(mh.x), bf2f(mh.y), bf2f(mh.z), bf2f(mh.w)};
        if (HASBN) {
            m[0] = fmaxf(cav[0] * m[0] + cbv[0], 0.f);
            m[1] = fmaxf(cav[1] * m[1] + cbv[1], 0.f);
            m[2] = fmaxf(cav[2] * m[2] + cbv[2], 0.f);
            m[3] = fmaxf(cav[3] * m[3] + cbv[3], 0.f);
        }
        m += beq[((cur >> 17) & 7u) * 16 + q];
        m += beq[(8 + ((cur >> 20) & 7u)) * 16 + q];
        m += beq[(16 + ((cur >> 23) & 7u)) * 16 + q];
        acc[0] += fmaxf(m[0], 0.f);
        acc[1] += fmaxf(m[1], 0.f);
        acc[2] += fmaxf(m[2], 0.f);
        acc[3] += fmaxf(m[3], 0.f);
    }
    ((floatx4*)agg)[(size_t)n * 16 + q] = acc;
}

// weights -> bf16 transposed (hi only; activation keeps split precision)
__global__ void wcvt(const float* __restrict__ W1, const float* __restrict__ W2,
                     unsigned short* __restrict__ w1h, unsigned short* __restrict__ w2h) {
    int id = blockIdx.x * 256 + threadIdx.x;
    if (id < 32768) {
        int l = id >> 13, rem = id & 8191, c = rem >> 6, k = rem & 63;
        w1h[id] = f2bf(W1[l * 8192 + k * 128 + c]);
    } else {
        int id2 = id - 32768;
        int l = id2 >> 13, rem = id2 & 8191, c = rem >> 7, k = rem & 127;
        w2h[id2] = f2bf(W2[l * 8192 + k * 64 + c]);
    }
}

#define MFMA __builtin_amdgcn_mfma_f32_16x16x32_bf16

// Gram pass: per-block partials of G_hh = Zh^T Zh, G_hl = Zh^T Zl over 256 nodes.
#define ZS 264   // LDS stride in shorts (256 + 8 pad)
__launch_bounds__(256)
__global__ void zstat(const float* __restrict__ z, float* __restrict__ Gpart,
                      float* __restrict__ zsum) {
    __shared__ char smem[67584];
    unsigned short* zh = (unsigned short*)smem;            // 64 x ZS
    unsigned short* zl = zh + 64 * ZS;
    int tid = threadIdx.x;
    int c2 = tid & 31;            // col-pair id
    int nof = tid >> 5;           // node sub-offset 0..7
    int wv = tid >> 6, lane = tid & 63, m = lane & 15, qd = lane >> 4;
    float2 csum = make_float2(0.f, 0.f);
    floatx4 acc[8];               // 4 j-tiles x {hh, hl}
    for (int t = 0; t < 8; t++) acc[t] = (floatx4){0.f, 0.f, 0.f, 0.f};
    int base = blockIdx.x * 256;
    for (int it = 0; it < 32; it++) {
        int n = it * 8 + nof;
        int node = base + n;
        float2 v = make_float2(0.f, 0.f);
        if (node < NN) v = ((const float2*)z)[(size_t)node * 32 + c2];
        csum.x += v.x; csum.y += v.y;
        unsigned short hx = f2bf(v.x), hy = f2bf(v.y);
        zh[(2 * c2) * ZS + n] = hx;
        zh[(2 * c2 + 1) * ZS + n] = hy;
        zl[(2 * c2) * ZS + n] = f2bf(v.x - bf2f(hx));
        zl[(2 * c2 + 1) * ZS + n] = f2bf(v.y - bf2f(hy));
    }
    __syncthreads();
    for (int kc = 0; kc < 8; kc++) {
        short8 ah = *(const short8*)&zh[(wv * 16 + m) * ZS + kc * 32 + qd * 8];
        for (int j = 0; j < 4; j++) {
            short8 bh = *(const short8*)&zh[(j * 16 + m) * ZS + kc * 32 + qd * 8];
            short8 bl = *(const short8*)&zl[(j * 16 + m) * ZS + kc * 32 + qd * 8];
            acc[j * 2]     = MFMA(ah, bh, acc[j * 2], 0, 0, 0);
            acc[j * 2 + 1] = MFMA(ah, bl, acc[j * 2 + 1], 0, 0, 0);
        }
    }
    float* gp = Gpart + (size_t)blockIdx.x * 8192;
    for (int j = 0; j < 4; j++)
        for (int r = 0; r < 4; r++) {
            int idx = (wv * 16 + qd * 4 + r) * 64 + j * 16 + m;
            gp[idx] = acc[j * 2][r];
            gp[4096 + idx] = acc[j * 2 + 1][r];
        }
    __syncthreads();               // all LDS reads done before overlay
    float* red = (float*)smem;
    red[tid] = csum.x; red[256 + tid] = csum.y;
    __syncthreads();
    if (tid < 32) {
        float sx = 0.f, sy = 0.f;
        for (int k = 0; k < 8; k++) { sx += red[k * 32 + tid]; sy += red[256 + k * 32 + tid]; }
        atomicAdd(&zsum[2 * tid], sx);
        atomicAdd(&zsum[2 * tid + 1], sy);
    }
}

// sum NZB partials -> G[8192] (per-layer, zeroed). grid (32, 4): y = partial-range.
__global__ void greduce(const float* __restrict__ Gpart, float* __restrict__ G) {
    int idx = blockIdx.x * 256 + threadIdx.x;   // 8192 outputs
    int b0 = blockIdx.y * 98;
    int b1 = b0 + 98; if (b1 > NZB) b1 = NZB;
    float s = 0.f;
    for (int b = b0; b < b1; b++) s += Gpart[(size_t)b * 8192 + idx];
    atomicAdd(&G[idx], s);
}

// stats1 from Gram, one block per channel c. Uses bf16-ROUNDED weights to match GEMM1.
__launch_bounds__(256)
__global__ void bn1stat(const float* __restrict__ W1, const float* __restrict__ b1,
                        const float* __restrict__ G, const float* __restrict__ zsum,
                        int l, double* __restrict__ stats) {
    __shared__ float wc[64];
    __shared__ float red[256];
    int c = blockIdx.x;
    int tid = threadIdx.x;
    if (tid < 64) wc[tid] = bf2f(f2bf(W1[l * 8192 + tid * 128 + c]));  // rounded W1[l][k][c]
    __syncthreads();
    float q = 0.f;
    for (int p = 0; p < 16; p++) {
        int idx = p * 256 + tid;           // coalesced over G
        int i = idx >> 6, j = idx & 63;
        q += wc[i] * wc[j] * (G[idx] + 2.f * G[4096 + idx]);
    }
    red[tid] = q;
    __syncthreads();
    for (int d = 128; d > 0; d >>= 1) {
        if (tid < d) red[tid] += red[tid + d];
        __syncthreads();
    }
    if (tid == 0) {
        float s1 = 0.f;
        for (int k = 0; k < 64; k++) s1 += zsum[k] * wc[k];
        float bc = b1[l * 128 + c];
        stats[c] = (double)s1 + (double)NN * bc;
        stats[128 + c] = (double)red[0] + 2.0 * bc * s1 + (double)NN * bc * bc;
    }
}

// Fused MLP: z -> GEMM1 -> bn1+relu -> GEMM2 -> t2 fp32 + bf16 mirror (+ t2 colstats)
// Weights bf16 (hi only); activations split hi/lo. LDS 53248 B -> 3 blocks/CU.
__launch_bounds__(256)
__global__ void mlp_fused(const float* __restrict__ z,
                          const unsigned short* __restrict__ w1h, const float* __restrict__ b1,
                          const unsigned short* __restrict__ w2h, const float* __restrict__ b2,
                          const float* __restrict__ bn_g, const float* __restrict__ bn_b,
                          const double* __restrict__ stats1, int l,
                          float* __restrict__ t2, unsigned short* __restrict__ t216,
                          double* __restrict__ stats2) {
    __shared__ char smem[53248];
    // phase A: zbh[0..9216) zbl[9216..18432) wth[18432..36864) bytes
    unsigned short* zbh = (unsigned short*)smem;
    unsigned short* zbl = zbh + 64 * 72;
    unsigned short* wth = zbl + 64 * 72;
    // phase B: rbh[0..17408) rbl[17408..34816) w2th[34816..52224) bytes
    unsigned short* rbh  = (unsigned short*)smem;
    unsigned short* rbl  = rbh + 64 * 136;
    unsigned short* w2th = rbl + 64 * 136;
    float* ca = (float*)(smem + 52224);   // [128] + [128]
    float* cb = ca + 128;
    int tid = threadIdx.x;
    int base = blockIdx.x * 64;

    if (tid < 128) {
        float mean = (float)(stats1[tid] / NN);
        float var  = (float)(stats1[128 + tid] / NN) - mean * mean;
        float a = bn_g[l * 128 + tid] * rsqrtf(var + 1e-5f);
        ca[tid] = a;
        cb[tid] = bn_b[l * 128 + tid] - mean * a + a * b1[l * 128 + tid];
    }
    const unsigned short* wsh = w1h + l * 8192;
    for (int it = 0; it < 4; it++) {
        int chunk = it * 256 + tid;
        int c = chunk >> 3, k0 = (chunk & 7) * 8;
        *(uint4*)&wth[c * 72 + k0] = *(const uint4*)(wsh + chunk * 8);
    }
    for (int it = 0; it < 8; it++) {
        int idx2 = (it * 256 + tid) * 2;
        int n = idx2 >> 6, col = idx2 & 63;
        int node = base + n;
        float2 v = make_float2(0.f, 0.f);
        if (node < NN) v = ((const float2*)z)[(size_t)node * 32 + (col >> 1)];
        unsigned short hx = f2bf(v.x), hy = f2bf(v.y);
        zbh[n * 72 + col] = hx;     zbh[n * 72 + col + 1] = hy;
        zbl[n * 72 + col] = f2bf(v.x - bf2f(hx));
        zbl[n * 72 + col + 1] = f2bf(v.y - bf2f(hy));
    }
    const unsigned short* w2sh = w2h + l * 8192;
    uint4 preH[4];
    for (int it = 0; it < 4; it++)
        preH[it] = *(const uint4*)(w2sh + (it * 256 + tid) * 8);
    __syncthreads();
    int wv = tid >> 6, lane = tid & 63, m = lane & 15, qd = lane >> 4;
    short8 ah0 = *(const short8*)&zbh[(wv * 16 + m) * 72 + qd * 8];
    short8 ah1 = *(const short8*)&zbh[(wv * 16 + m) * 72 + 32 + qd * 8];
    short8 al0 = *(const short8*)&zbl[(wv * 16 + m) * 72 + qd * 8];
    short8 al1 = *(const short8*)&zbl[(wv * 16 + m) * 72 + 32 + qd * 8];
    floatx4 acc1[8];
    for (int t = 0; t < 8; t++) {
        short8 bh0 = *(const short8*)&wth[(t * 16 + m) * 72 + qd * 8];
        short8 bh1 = *(const short8*)&wth[(t * 16 + m) * 72 + 32 + qd * 8];
        floatx4 c0 = {0.f, 0.f, 0.f, 0.f};
        c0 = MFMA(ah0, bh0, c0, 0, 0, 0);
        c0 = MFMA(al0, bh0, c0, 0, 0, 0);
        c0 = MFMA(ah1, bh1, c0, 0, 0, 0);
        c0 = MFMA(al1, bh1, c0, 0, 0, 0);
        acc1[t] = c0;
    }
    __syncthreads();
    for (int it = 0; it < 4; it++) {
        int chunk = it * 256 + tid;
        int c = chunk >> 4, k0 = (chunk & 15) * 8;
        *(uint4*)&w2th[c * 136 + k0] = preH[it];
    }
    for (int t = 0; t < 8; t++) {
        int col = t * 16 + m;
        float a = ca[col], b = cb[col];
        for (int r = 0; r < 4; r++) {
            int row = wv * 16 + qd * 4 + r;
            float rv = fmaxf(a * acc1[t][r] + b, 0.f);
            unsigned short hh = f2bf(rv);
            rbh[row * 136 + col] = hh;
            rbl[row * 136 + col] = f2bf(rv - bf2f(hh));
        }
    }
    __syncthreads();
    short8 ah[4], al[4];
    for (int kh = 0; kh < 4; kh++) {
        ah[kh] = *(const short8*)&rbh[(wv * 16 + m) * 136 + kh * 32 + qd * 8];
        al[kh] = *(const short8*)&rbl[(wv * 16 + m) * 136 + kh * 32 + qd * 8];
    }
    floatx4 acc2[4];
    for (int t = 0; t < 4; t++) {
        floatx4 c0 = {0.f, 0.f, 0.f, 0.f};
        for (int kh = 0; kh < 4; kh++) {
            short8 bh = *(const short8*)&w2th[(t * 16 + m) * 136 + kh * 32 + qd * 8];
            c0 = MFMA(ah[kh], bh, c0, 0, 0, 0);
            c0 = MFMA(al[kh], bh, c0, 0, 0, 0);
        }
        acc2[t] = c0;
    }
    __syncthreads();
    float* redS = (float*)smem;
    float* redQ = redS + 1024;
    const float* bias = b2 + l * 64;
    int g = wv * 4 + qd;
    for (int t = 0; t < 4; t++) {
        int col = t * 16 + m;
        float bv = bias[col];
        float s = 0.f, ss = 0.f;
        for (int r = 0; r < 4; r++) {
            int node = base + wv * 16 + qd * 4 + r;
            if (node < NN) {
                float v = acc2[t][r] + bv;
                t2[(size_t)node * 64 + col] = v;
                t216[(size_t)node * 64 + col] = f2bf(v);
                s += v; ss += v * v;
            }
        }
        redS[col * 16 + g] = s;
        redQ[col * 16 + g] = ss;
    }
    __syncthreads();
    if (tid < 64) {
        float s = 0.f, ss = 0.f;
        for (int gg = 0; gg < 16; gg++) { s += redS[tid * 16 + gg]; ss += redQ[tid * 16 + gg]; }
        atomicAdd(&stats2[tid], (double)s);
        atomicAdd(&stats2[64 + tid], (double)ss);
    }
}

__global__ void bnapply_last(const float* __restrict__ t2, const float* __restrict__ bn_g,
                             const float* __restrict__ bn_b, const double* __restrict__ stats,
                             float* __restrict__ out, float* __restrict__ gsum,
                             float* __restrict__ gcnt, const int* __restrict__ batch) {
    __shared__ float ca[64], cb[64];
    int tid = threadIdx.x;
    if (tid < 64) {
        float mean = (float)(stats[tid] / NN);
        float var  = (float)(stats[64 + tid] / NN) - mean * mean;
        float a = bn_g[3 * 64 + tid] * rsqrtf(var + 1e-5f);
        ca[tid] = a;
        cb[tid] = bn_b[3 * 64 + tid] - mean * a;
    }
    __syncthreads();
    size_t base = (size_t)blockIdx.x * 4096;
    for (int it = 0; it < 16; it++) {
        size_t idx = base + it * 256 + tid;
        if (idx >= (size_t)NN * 64) return;
        int c = (int)(idx & 63);
        float v = ca[c] * t2[idx] + cb[c];
        out[idx] = v;
        int g = batch[idx >> 6];
        atomicAdd(&gsum[(size_t)g * 64 + c], v);
        if (c == 0) atomicAdd(&gcnt[g], 1.0f);
    }
}

__global__ void pool_div(const float* __restrict__ gsum, const float* __restrict__ gcnt,
                         float* __restrict__ out) {
    int id = blockIdx.x * 256 + threadIdx.x;
    int g = id >> 6;
    out[(size_t)NN * 64 + id] = gsum[id] / (gcnt[g] + 1e-9f);
}

extern "C" void kernel_launch(void* const* d_in, const int* in_sizes, int n_in,
                              void* d_out, int out_size, void* d_ws, size_t ws_size,
                              hipStream_t stream) {
    const float* atom_emb = (const float*)d_in[0];
    const float* bond_emb = (const float*)d_in[1];
    const float* eps      = (const float*)d_in[2];
    const float* W1       = (const float*)d_in[3];
    const float* b1       = (const float*)d_in[4];
    const float* bn1_g    = (const float*)d_in[5];
    const float* bn1_b    = (const float*)d_in[6];
    const float* W2       = (const float*)d_in[7];
    const float* b2       = (const float*)d_in[8];
    const float* bn2_g    = (const float*)d_in[9];
    const float* bn2_b    = (const float*)d_in[10];
    const int* x_feat     = (const int*)d_in[11];
    const int* edge_index = (const int*)d_in[12];
    const int* edge_attr  = (const int*)d_in[13];
    const int* batch      = (const int*)d_in[14];
    float* out = (float*)d_out;

    char* ws = (char*)d_ws;
    // ---- zero region (one memset) ----
    double* stats = (double*)ws;  ws += 2048 * 8;            // 8 slots x 256 doubles
    float* gsum   = (float*)ws;   ws += (size_t)NB * 64 * 4;
    float* gcnt   = (float*)ws;   ws += NB * 4;
    int* csr      = (int*)ws;     ws += (size_t)NN * 4;
    float* zsum   = (float*)ws;   ws += 4 * 64 * 4;
    float* G      = (float*)ws;   ws += (size_t)4 * 8192 * 4;  // per-layer [Ghh|Ghl]
    size_t zbytes = (size_t)(ws - (char*)d_ws);
    // ---- rest ----
    int* bsum       = (int*)ws;       ws += 128 * 4;
    unsigned* epack = (unsigned*)ws;  ws += (size_t)NE * 4;
    float* Gpart = (float*)ws;    ws += (size_t)NZB * 8192 * 4;
    float* xbuf = (float*)ws;     ws += (size_t)NN * 64 * 4;   // h (l=0) / t2 (l>=1), fp32
    unsigned short* x16 = (unsigned short*)ws; ws += (size_t)NN * 64 * 2;  // bf16 mirror
    float* agg  = (float*)ws;     ws += (size_t)NN * 64 * 4;
    unsigned short* w1h = (unsigned short*)ws; ws += 32768 * 2;
    unsigned short* w2h = (unsigned short*)ws; ws += 32768 * 2;

    hipMemsetAsync((void*)stats, 0, zbytes, stream);

    wcvt<<<256, 256, 0, stream>>>(W1, W2, w1h, w2h);
    deg_count<<<4883, 256, 0, stream>>>(edge_index, csr);
    scan_local<<<98, 256, 0, stream>>>(csr, bsum);
    scan_bsum<<<1, 128, 0, stream>>>(bsum);
    scan_add<<<98, 256, 0, stream>>>(csr, bsum);
    csr_fill<<<4883, 256, 0, stream>>>(edge_index, edge_attr, csr, epack);
    atom_encode<<<6250, 256, 0, stream>>>(atom_emb, x_feat, xbuf, x16);

    for (int l = 0; l < 4; l++) {
        double* s1 = stats + (size_t)(l * 2) * 256;
        double* s2 = stats + (size_t)(l * 2 + 1) * 256;
        if (l == 0) {
            gather_k<false><<<6250, 256, 0, stream>>>(xbuf, x16, bond_emb, eps, csr, epack, l,
                                                      nullptr, nullptr, nullptr, agg);
        } else {
            double* sp = stats + (size_t)((l - 1) * 2 + 1) * 256;
            gather_k<true><<<6250, 256, 0, stream>>>(xbuf, x16, bond_emb, eps, csr, epack, l,
                                                     sp, bn2_g, bn2_b, agg);
        }
        float* Gl = G + (size_t)l * 8192;
        zstat<<<NZB, 256, 0, stream>>>(agg, Gpart, zsum + l * 64);
        greduce<<<dim3(32, 4), 256, 0, stream>>>(Gpart, Gl);
        bn1stat<<<128, 256, 0, stream>>>(W1, b1, Gl, zsum + l * 64, l, s1);
        mlp_fused<<<1563, 256, 0, stream>>>(agg, w1h, b1, w2h, b2,
                                            bn1_g, bn1_b, s1, l, xbuf, x16, s2);
    }
    bnapply_last<<<1563, 256, 0, stream>>>(xbuf, bn2_g, bn2_b,
                                           stats + (size_t)(3 * 2 + 1) * 256,
                                           out, gsum, gcnt, batch);
    pool_div<<<512, 256, 0, stream>>>(gsum, gcnt, out);
}

// Round 11
// 918.181 us; speedup vs baseline: 1.5281x; 1.0251x over previous
//
#include <hip/hip_runtime.h>

#define NN 100000
#define NE 1250000
#define NB 2048
#define NZB 391    // zstat blocks (391*256 = 100096 >= NN)

typedef __attribute__((ext_vector_type(8))) short short8;
typedef __attribute__((ext_vector_type(4))) float floatx4;

__device__ inline unsigned short f2bf(float f) {
    unsigned u = __float_as_uint(f);
    u = u + 0x7fffu + ((u >> 16) & 1u);   // RNE
    return (unsigned short)(u >> 16);
}
__device__ inline float bf2f(unsigned short h) {
    return __uint_as_float(((unsigned)h) << 16);
}

// h[n][d] = sum_f atom_emb[f][x_feat[n][f]][d]  (fp32 + bf16 mirror)
__global__ void atom_encode(const float* __restrict__ atom_emb,
                            const int* __restrict__ x_feat,
                            float* __restrict__ h, unsigned short* __restrict__ h16) {
    int id = blockIdx.x * 256 + threadIdx.x;   // N*16 exact
    int n = id >> 4, q = id & 15;
    floatx4 acc = {0.f, 0.f, 0.f, 0.f};
    for (int f = 0; f < 9; f++) {
        int v = x_feat[n * 9 + f];
        const floatx4* p = (const floatx4*)(atom_emb + (size_t)(f * 128 + v) * 64);
        acc += p[q];
    }
    ((floatx4*)h)[(size_t)n * 16 + q] = acc;
    ushort4 hv;
    hv.x = f2bf(acc[0]); hv.y = f2bf(acc[1]); hv.z = f2bf(acc[2]); hv.w = f2bf(acc[3]);
    ((ushort4*)h16)[(size_t)n * 16 + q] = hv;
}

// ---- CSR build ----
__global__ void deg_count(const int* __restrict__ ei, int* __restrict__ csr) {
    int e = blockIdx.x * 256 + threadIdx.x;
    if (e < NE) atomicAdd(&csr[ei[NE + e]], 1);
}

__global__ void scan_local(int* __restrict__ csr, int* __restrict__ bsum) {
    __shared__ int ls[256];
    int tid = threadIdx.x;
    int base = blockIdx.x * 1024 + tid * 4;
    int4 v = make_int4(0, 0, 0, 0);
    if (base + 3 < NN) {
        v = *(const int4*)(csr + base);
    } else {
        if (base + 0 < NN) v.x = csr[base + 0];
        if (base + 1 < NN) v.y = csr[base + 1];
        if (base + 2 < NN) v.z = csr[base + 2];
        if (base + 3 < NN) v.w = csr[base + 3];
    }
    int s = v.x + v.y + v.z + v.w;
    ls[tid] = s;
    __syncthreads();
    for (int d = 1; d < 256; d <<= 1) {
        int t = (tid >= d) ? ls[tid - d] : 0;
        __syncthreads();
        ls[tid] += t;
        __syncthreads();
    }
    if (tid == 255) bsum[blockIdx.x] = ls[255];
    int e0 = tid ? ls[tid - 1] : 0;
    int4 w;
    w.x = e0; w.y = e0 + v.x; w.z = w.y + v.y; w.w = w.z + v.z;
    if (base + 3 < NN) {
        *(int4*)(csr + base) = w;
    } else {
        if (base + 0 < NN) csr[base + 0] = w.x;
        if (base + 1 < NN) csr[base + 1] = w.y;
        if (base + 2 < NN) csr[base + 2] = w.z;
        if (base + 3 < NN) csr[base + 3] = w.w;
    }
}

__global__ void scan_bsum(int* __restrict__ bsum) {
    __shared__ int ls[128];
    int tid = threadIdx.x;
    int v = (tid < 98) ? bsum[tid] : 0;
    ls[tid] = v;
    __syncthreads();
    for (int d = 1; d < 128; d <<= 1) {
        int t = (tid >= d) ? ls[tid - d] : 0;
        __syncthreads();
        ls[tid] += t;
        __syncthreads();
    }
    if (tid < 98) bsum[tid] = tid ? ls[tid - 1] : 0;
}

__global__ void scan_add(int* __restrict__ csr, const int* __restrict__ bsum) {
    int off = bsum[blockIdx.x];
    int base = blockIdx.x * 1024 + threadIdx.x * 4;
    if (base + 3 < NN) {
        int4 v = *(const int4*)(csr + base);
        v.x += off; v.y += off; v.z += off; v.w += off;
        *(int4*)(csr + base) = v;
    } else {
        for (int i = 0; i < 4; i++)
            if (base + i < NN) csr[base + i] += off;
    }
}

// packed record: src (17b) | a0 (3b) | a1 (3b) | a2 (3b)
// XCD-sharded: shard = blockIdx&7 handles dst in [shard*12500, shard*12500+12500).
// With round-robin block->XCD dispatch each XCD writes a contiguous 625 KB epack
// slice that stays L2-resident -> full line accumulation before writeback.
// Correct regardless of actual dispatch mapping (pure filter).
__global__ void csr_fill(const int* __restrict__ ei, const int* __restrict__ ea,
                         int* __restrict__ csr, unsigned* __restrict__ epack) {
    int shard = blockIdx.x & 7;
    int e = (blockIdx.x >> 3) * 256 + threadIdx.x;
    if (e >= NE) return;
    int dst = ei[NE + e];
    if (dst / 12500 != shard) return;
    int pos = atomicAdd(&csr[dst], 1);
    unsigned at = (unsigned)(ea[e * 3] | (ea[e * 3 + 1] << 3) | (ea[e * 3 + 2] << 6));
    epack[pos] = (unsigned)ei[e] | (at << 17);
}

// agg[n] = (1+eps)*h[n] + sum_{e: dst==n} relu(h[src_e] + bond(e))
// self-term fp32; neighbors from bf16 mirror. 2-way ILP: edge pairs, two acc chains.
template <bool HASBN>
__global__ void gather_k(const float* __restrict__ x, const unsigned short* __restrict__ x16,
                         const float* __restrict__ bond_emb,
                         const float* __restrict__ eps, const int* __restrict__ csr,
                         const unsigned* __restrict__ epack, int l,
                         const double* __restrict__ stats, const float* __restrict__ bn_g,
                         const float* __restrict__ bn_b, float* __restrict__ agg) {
    __shared__ float be[24 * 64];
    __shared__ float ca[64], cb[64];
    int tid = threadIdx.x;
    const float* bsrc = bond_emb + (size_t)l * 1536;
    for (int i = tid; i < 1536; i += 256) be[i] = bsrc[i];
    if (tid < 64) {
        if (HASBN) {
            float mean = (float)(stats[tid] / NN);
            float var  = (float)(stats[64 + tid] / NN) - mean * mean;
            float a = bn_g[(l - 1) * 64 + tid] * rsqrtf(var + 1e-5f);
            ca[tid] = a;
            cb[tid] = bn_b[(l - 1) * 64 + tid] - mean * a;
        } else {
            ca[tid] = 1.f; cb[tid] = 0.f;
        }
    }
    __syncthreads();
    int id = blockIdx.x * 256 + tid;           // NN*16 exact
    int n = id >> 4, q = id & 15;
    float s = 1.0f + eps[l];
    floatx4 cav = *(const floatx4*)&ca[q * 4];
    floatx4 cbv = *(const floatx4*)&cb[q * 4];
    floatx4 xv = ((const floatx4*)x)[(size_t)n * 16 + q];
    if (HASBN) {
        xv[0] = fmaxf(cav[0] * xv[0] + cbv[0], 0.f);
        xv[1] = fmaxf(cav[1] * xv[1] + cbv[1], 0.f);
        xv[2] = fmaxf(cav[2] * xv[2] + cbv[2], 0.f);
        xv[3] = fmaxf(cav[3] * xv[3] + cbv[3], 0.f);
    }
    floatx4 acc = xv * s;
    floatx4 accB = {0.f, 0.f, 0.f, 0.f};
    int k0 = n ? csr[n - 1] : 0;
    int k1 = csr[n];
    const floatx4* beq = (const floatx4*)be;
    int k = k0;
    for (; k + 1 < k1; k += 2) {
        unsigned r0 = epack[k];
        unsigned r1 = epack[k + 1];
        ushort4 h0 = ((const ushort4*)x16)[(size_t)(r0 & 0x1FFFFu) * 16 + q];
        ushort4 h1 = ((const ushort4*)x16)[(size_t)(r1 & 0x1FFFFu) * 16 + q];
        floatx4 m0 = {bf2f(h0.x), bf2f(h0.y), bf2f(h0.z), bf2f(h0.w)};
        floatx4 m1 = {bf2f(h1.x), bf2f(h1.y), bf2f(h1.z), bf2f(h1.w)};
        if (HASBN) {
            m0[0] = fmaxf(cav[0] * m0[0] + cbv[0], 0.f);
            m0[1] = fmaxf(cav[1] * m0[1] + cbv[1], 0.f);
            m0[2] = fmaxf(cav[2] * m0[2] + cbv[2], 0.f);
            m0[3] = fmaxf(cav[3] * m0[3] + cbv[3], 0.f);
            m1[0] = fmaxf(cav[0] * m1[0] + cbv[0], 0.f);
            m1[1] = fmaxf(cav[1] * m1[1] + cbv[1], 0.f);
            m1[2] = fmaxf(cav[2] * m1[2] + cbv[2], 0.f);
            m1[3] = fmaxf(cav[3] * m1[3] + cbv[3], 0.f);
        }
        m0 += beq[((r0 >> 17) & 7u) * 16 + q];
        m0 += beq[(8 + ((r0 >> 20) & 7u)) * 16 + q];
        m0 += beq[(16 + ((r0 >> 23) & 7u)) * 16 + q];
        m1 += beq[((r1 >> 17) & 7u) * 16 + q];
        m1 += beq[(8 + ((r1 >> 20) & 7u)) * 16 + q];
        m1 += beq[(16 + ((r1 >> 23) & 7u)) * 16 + q];
        acc[0] += fmaxf(m0[0], 0.f);
        acc[1] += fmaxf(m0[1], 0.f);
        acc[2] += fmaxf(m0[2], 0.f);
        acc[3] += fmaxf(m0[3], 0.f);
        accB[0] += fmaxf(m1[0], 0.f);
        accB[1] += fmaxf(m1[1], 0.f);
        accB[2] += fmaxf(m1[2], 0.f);
        accB[3] += fmaxf(m1[3], 0.f);
    }
    if (k < k1) {
        unsigned r0 = epack[k];
        ushort4 h0 = ((const ushort4*)x16)[(size_t)(r0 & 0x1FFFFu) * 16 + q];
        floatx4 m0 = {bf2f(h0.x), bf2f(h0.y), bf2f(h0.z), bf2f(h0.w)};
        if (HASBN) {
            m0[0] = fmaxf(cav[0] * m0[0] + cbv[0], 0.f);
            m0[1] = fmaxf(cav[1] * m0[1] + cbv[1], 0.f);
            m0[2] = fmaxf(cav[2] * m0[2] + cbv[2], 0.f);
            m0[3] = fmaxf(cav[3] * m0[3] + cbv[3], 0.f);
        }
        m0 += beq[((r0 >> 17) & 7u) * 16 + q];
        m0 += beq[(8 + ((r0 >> 20) & 7u)) * 16 + q];
        m0 += beq[(16 + ((r0 >> 23) & 7u)) * 16 + q];
        acc[0] += fmaxf(m0[0], 0.f);
        acc[1] += fmaxf(m0[1], 0.f);
        acc[2] += fmaxf(m0[2], 0.f);
        acc[3] += fmaxf(m0[3], 0.f);
    }
    acc += accB;
    ((floatx4*)agg)[(size_t)n * 16 + q] = acc;
}

// weights -> bf16 transposed (hi only; activation keeps split precision)
__global__ void wcvt(const float* __restrict__ W1, const float* __restrict__ W2,
                     unsigned short* __restrict__ w1h, unsigned short* __restrict__ w2h) {
    int id = blockIdx.x * 256 + threadIdx.x;
    if (id < 32768) {
        int l = id >> 13, rem = id & 8191, c = rem >> 6, k = rem & 63;
        w1h[id] = f2bf(W1[l * 8192 + k * 128 + c]);
    } else {
        int id2 = id - 32768;
        int l = id2 >> 13, rem = id2 & 8191, c = rem >> 7, k = rem & 127;
        w2h[id2] = f2bf(W2[l * 8192 + k * 64 + c]);
    }
}

#define MFMA __builtin_amdgcn_mfma_f32_16x16x32_bf16

// Gram pass: per-block partials of G_hh = Zh^T Zh, G_hl = Zh^T Zl over 256 nodes.
#define ZS 264   // LDS stride in shorts (256 + 8 pad)
__launch_bounds__(256)
__global__ void zstat(const float* __restrict__ z, float* __restrict__ Gpart,
                      float* __restrict__ zsum) {
    __shared__ char smem[67584];
    unsigned short* zh = (unsigned short*)smem;            // 64 x ZS
    unsigned short* zl = zh + 64 * ZS;
    int tid = threadIdx.x;
    int c2 = tid & 31;            // col-pair id
    int nof = tid >> 5;           // node sub-offset 0..7
    int wv = tid >> 6, lane = tid & 63, m = lane & 15, qd = lane >> 4;
    float2 csum = make_float2(0.f, 0.f);
    floatx4 acc[8];               // 4 j-tiles x {hh, hl}
    for (int t = 0; t < 8; t++) acc[t] = (floatx4){0.f, 0.f, 0.f, 0.f};
    int base = blockIdx.x * 256;
    for (int it = 0; it < 32; it++) {
        int n = it * 8 + nof;
        int node = base + n;
        float2 v = make_float2(0.f, 0.f);
        if (node < NN) v = ((const float2*)z)[(size_t)node * 32 + c2];
        csum.x += v.x; csum.y += v.y;
        unsigned short hx = f2bf(v.x), hy = f2bf(v.y);
        zh[(2 * c2) * ZS + n] = hx;
        zh[(2 * c2 + 1) * ZS + n] = hy;
        zl[(2 * c2) * ZS + n] = f2bf(v.x - bf2f(hx));
        zl[(2 * c2 + 1) * ZS + n] = f2bf(v.y - bf2f(hy));
    }
    __syncthreads();
    for (int kc = 0; kc < 8; kc++) {
        short8 ah = *(const short8*)&zh[(wv * 16 + m) * ZS + kc * 32 + qd * 8];
        for (int j = 0; j < 4; j++) {
            short8 bh = *(const short8*)&zh[(j * 16 + m) * ZS + kc * 32 + qd * 8];
            short8 bl = *(const short8*)&zl[(j * 16 + m) * ZS + kc * 32 + qd * 8];
            acc[j * 2]     = MFMA(ah, bh, acc[j * 2], 0, 0, 0);
            acc[j * 2 + 1] = MFMA(ah, bl, acc[j * 2 + 1], 0, 0, 0);
        }
    }
    float* gp = Gpart + (size_t)blockIdx.x * 8192;
    for (int j = 0; j < 4; j++)
        for (int r = 0; r < 4; r++) {
            int idx = (wv * 16 + qd * 4 + r) * 64 + j * 16 + m;
            gp[idx] = acc[j * 2][r];
            gp[4096 + idx] = acc[j * 2 + 1][r];
        }
    __syncthreads();               // all LDS reads done before overlay
    float* red = (float*)smem;
    red[tid] = csum.x; red[256 + tid] = csum.y;
    __syncthreads();
    if (tid < 32) {
        float sx = 0.f, sy = 0.f;
        for (int k = 0; k < 8; k++) { sx += red[k * 32 + tid]; sy += red[256 + k * 32 + tid]; }
        atomicAdd(&zsum[2 * tid], sx);
        atomicAdd(&zsum[2 * tid + 1], sy);
    }
}

// sum NZB partials -> G[8192] (per-layer, zeroed). grid (32, 4): y = partial-range.
__global__ void greduce(const float* __restrict__ Gpart, float* __restrict__ G) {
    int idx = blockIdx.x * 256 + threadIdx.x;   // 8192 outputs
    int b0 = blockIdx.y * 98;
    int b1 = b0 + 98; if (b1 > NZB) b1 = NZB;
    float s = 0.f;
    for (int b = b0; b < b1; b++) s += Gpart[(size_t)b * 8192 + idx];
    atomicAdd(&G[idx], s);
}

// stats1 from Gram, one block per channel c. Uses bf16-ROUNDED weights to match GEMM1.
__launch_bounds__(256)
__global__ void bn1stat(const float* __restrict__ W1, const float* __restrict__ b1,
                        const float* __restrict__ G, const float* __restrict__ zsum,
                        int l, double* __restrict__ stats) {
    __shared__ float wc[64];
    __shared__ float red[256];
    int c = blockIdx.x;
    int tid = threadIdx.x;
    if (tid < 64) wc[tid] = bf2f(f2bf(W1[l * 8192 + tid * 128 + c]));  // rounded W1[l][k][c]
    __syncthreads();
    float q = 0.f;
    for (int p = 0; p < 16; p++) {
        int idx = p * 256 + tid;           // coalesced over G
        int i = idx >> 6, j = idx & 63;
        q += wc[i] * wc[j] * (G[idx] + 2.f * G[4096 + idx]);
    }
    red[tid] = q;
    __syncthreads();
    for (int d = 128; d > 0; d >>= 1) {
        if (tid < d) red[tid] += red[tid + d];
        __syncthreads();
    }
    if (tid == 0) {
        float s1 = 0.f;
        for (int k = 0; k < 64; k++) s1 += zsum[k] * wc[k];
        float bc = b1[l * 128 + c];
        stats[c] = (double)s1 + (double)NN * bc;
        stats[128 + c] = (double)red[0] + 2.0 * bc * s1 + (double)NN * bc * bc;
    }
}

// Fused MLP: z -> GEMM1 -> bn1+relu -> GEMM2 -> t2 fp32 + bf16 mirror (+ t2 colstats)
// Weights bf16 (hi only); activations split hi/lo. LDS 53248 B -> 3 blocks/CU.
__launch_bounds__(256)
__global__ void mlp_fused(const float* __restrict__ z,
                          const unsigned short* __restrict__ w1h, const float* __restrict__ b1,
                          const unsigned short* __restrict__ w2h, const float* __restrict__ b2,
                          const float* __restrict__ bn_g, const float* __restrict__ bn_b,
                          const double* __restrict__ stats1, int l,
                          float* __restrict__ t2, unsigned short* __restrict__ t216,
                          double* __restrict__ stats2) {
    __shared__ char smem[53248];
    unsigned short* zbh = (unsigned short*)smem;
    unsigned short* zbl = zbh + 64 * 72;
    unsigned short* wth = zbl + 64 * 72;
    unsigned short* rbh  = (unsigned short*)smem;
    unsigned short* rbl  = rbh + 64 * 136;
    unsigned short* w2th = rbl + 64 * 136;
    float* ca = (float*)(smem + 52224);   // [128] + [128]
    float* cb = ca + 128;
    int tid = threadIdx.x;
    int base = blockIdx.x * 64;

    if (tid < 128) {
        float mean = (float)(stats1[tid] / NN);
        float var  = (float)(stats1[128 + tid] / NN) - mean * mean;
        float a = bn_g[l * 128 + tid] * rsqrtf(var + 1e-5f);
        ca[tid] = a;
        cb[tid] = bn_b[l * 128 + tid] - mean * a + a * b1[l * 128 + tid];
    }
    const unsigned short* wsh = w1h + l * 8192;
    for (int it = 0; it < 4; it++) {
        int chunk = it * 256 + tid;
        int c = chunk >> 3, k0 = (chunk & 7) * 8;
        *(uint4*)&wth[c * 72 + k0] = *(const uint4*)(wsh + chunk * 8);
    }
    for (int it = 0; it < 8; it++) {
        int idx2 = (it * 256 + tid) * 2;
        int n = idx2 >> 6, col = idx2 & 63;
        int node = base + n;
        float2 v = make_float2(0.f, 0.f);
        if (node < NN) v = ((const float2*)z)[(size_t)node * 32 + (col >> 1)];
        unsigned short hx = f2bf(v.x), hy = f2bf(v.y);
        zbh[n * 72 + col] = hx;     zbh[n * 72 + col + 1] = hy;
        zbl[n * 72 + col] = f2bf(v.x - bf2f(hx));
        zbl[n * 72 + col + 1] = f2bf(v.y - bf2f(hy));
    }
    const unsigned short* w2sh = w2h + l * 8192;
    uint4 preH[4];
    for (int it = 0; it < 4; it++)
        preH[it] = *(const uint4*)(w2sh + (it * 256 + tid) * 8);
    __syncthreads();
    int wv = tid >> 6, lane = tid & 63, m = lane & 15, qd = lane >> 4;
    short8 ah0 = *(const short8*)&zbh[(wv * 16 + m) * 72 + qd * 8];
    short8 ah1 = *(const short8*)&zbh[(wv * 16 + m) * 72 + 32 + qd * 8];
    short8 al0 = *(const short8*)&zbl[(wv * 16 + m) * 72 + qd * 8];
    short8 al1 = *(const short8*)&zbl[(wv * 16 + m) * 72 + 32 + qd * 8];
    floatx4 acc1[8];
    for (int t = 0; t < 8; t++) {
        short8 bh0 = *(const short8*)&wth[(t * 16 + m) * 72 + qd * 8];
        short8 bh1 = *(const short8*)&wth[(t * 16 + m) * 72 + 32 + qd * 8];
        floatx4 c0 = {0.f, 0.f, 0.f, 0.f};
        c0 = MFMA(ah0, bh0, c0, 0, 0, 0);
        c0 = MFMA(al0, bh0, c0, 0, 0, 0);
        c0 = MFMA(ah1, bh1, c0, 0, 0, 0);
        c0 = MFMA(al1, bh1, c0, 0, 0, 0);
        acc1[t] = c0;
    }
    __syncthreads();
    for (int it = 0; it < 4; it++) {
        int chunk = it * 256 + tid;
        int c = chunk >> 4, k0 = (chunk & 15) * 8;
        *(uint4*)&w2th[c * 136 + k0] = preH[it];
    }
    for (int t = 0; t < 8; t++) {
        int col = t * 16 + m;
        float a = ca[col], b = cb[col];
        for (int r = 0; r < 4; r++) {
            int row = wv * 16 + qd * 4 + r;
            float rv = fmaxf(a * acc1[t][r] + b, 0.f);
            unsigned short hh = f2bf(rv);
            rbh[row * 136 + col] = hh;
            rbl[row * 136 + col] = f2bf(rv - bf2f(hh));
        }
    }
    __syncthreads();
    short8 ah[4], al[4];
    for (int kh = 0; kh < 4; kh++) {
        ah[kh] = *(const short8*)&rbh[(wv * 16 + m) * 136 + kh * 32 + qd * 8];
        al[kh] = *(const short8*)&rbl[(wv * 16 + m) * 136 + kh * 32 + qd * 8];
    }
    floatx4 acc2[4];
    for (int t = 0; t < 4; t++) {
        floatx4 c0 = {0.f, 0.f, 0.f, 0.f};
        for (int kh = 0; kh < 4; kh++) {
            short8 bh = *(const short8*)&w2th[(t * 16 + m) * 136 + kh * 32 + qd * 8];
            c0 = MFMA(ah[kh], bh, c0, 0, 0, 0);
            c0 = MFMA(al[kh], bh, c0, 0, 0, 0);
        }
        acc2[t] = c0;
    }
    __syncthreads();
    float* redS = (float*)smem;
    float* redQ = redS + 1024;
    const float* bias = b2 + l * 64;
    int g = wv * 4 + qd;
    for (int t = 0; t < 4; t++) {
        int col = t * 16 + m;
        float bv = bias[col];
        float s = 0.f, ss = 0.f;
        for (int r = 0; r < 4; r++) {
            int node = base + wv * 16 + qd * 4 + r;
            if (node < NN) {
                float v = acc2[t][r] + bv;
                t2[(size_t)node * 64 + col] = v;
                t216[(size_t)node * 64 + col] = f2bf(v);
                s += v; ss += v * v;
            }
        }
        redS[col * 16 + g] = s;
        redQ[col * 16 + g] = ss;
    }
    __syncthreads();
    if (tid < 64) {
        float s = 0.f, ss = 0.f;
        for (int gg = 0; gg < 16; gg++) { s += redS[tid * 16 + gg]; ss += redQ[tid * 16 + gg]; }
        atomicAdd(&stats2[tid], (double)s);
        atomicAdd(&stats2[64 + tid], (double)ss);
    }
}

__global__ void bnapply_last(const float* __restrict__ t2, const float* __restrict__ bn_g,
                             const float* __restrict__ bn_b, const double* __restrict__ stats,
                             float* __restrict__ out, float* __restrict__ gsum,
                             float* __restrict__ gcnt, const int* __restrict__ batch) {
    __shared__ float ca[64], cb[64];
    int tid = threadIdx.x;
    if (tid < 64) {
        float mean = (float)(stats[tid] / NN);
        float var  = (float)(stats[64 + tid] / NN) - mean * mean;
        float a = bn_g[3 * 64 + tid] * rsqrtf(var + 1e-5f);
        ca[tid] = a;
        cb[tid] = bn_b[3 * 64 + tid] - mean * a;
    }
    __syncthreads();
    size_t base = (size_t)blockIdx.x * 4096;
    for (int it = 0; it < 16; it++) {
        size_t idx = base + it * 256 + tid;
        if (idx >= (size_t)NN * 64) return;
        int c = (int)(idx & 63);
        float v = ca[c] * t2[idx] + cb[c];
        out[idx] = v;
        int g = batch[idx >> 6];
        atomicAdd(&gsum[(size_t)g * 64 + c], v);
        if (c == 0) atomicAdd(&gcnt[g], 1.0f);
    }
}

__global__ void pool_div(const float* __restrict__ gsum, const float* __restrict__ gcnt,
                         float* __restrict__ out) {
    int id = blockIdx.x * 256 + threadIdx.x;
    int g = id >> 6;
    out[(size_t)NN * 64 + id] = gsum[id] / (gcnt[g] + 1e-9f);
}

extern "C" void kernel_launch(void* const* d_in, const int* in_sizes, int n_in,
                              void* d_out, int out_size, void* d_ws, size_t ws_size,
                              hipStream_t stream) {
    const float* atom_emb = (const float*)d_in[0];
    const float* bond_emb = (const float*)d_in[1];
    const float* eps      = (const float*)d_in[2];
    const float* W1       = (const float*)d_in[3];
    const float* b1       = (const float*)d_in[4];
    const float* bn1_g    = (const float*)d_in[5];
    const float* bn1_b    = (const float*)d_in[6];
    const float* W2       = (const float*)d_in[7];
    const float* b2       = (const float*)d_in[8];
    const float* bn2_g    = (const float*)d_in[9];
    const float* bn2_b    = (const float*)d_in[10];
    const int* x_feat     = (const int*)d_in[11];
    const int* edge_index = (const int*)d_in[12];
    const int* edge_attr  = (const int*)d_in[13];
    const int* batch      = (const int*)d_in[14];
    float* out = (float*)d_out;

    char* ws = (char*)d_ws;
    // ---- zero region (one memset) ----
    double* stats = (double*)ws;  ws += 2048 * 8;            // 8 slots x 256 doubles
    float* gsum   = (float*)ws;   ws += (size_t)NB * 64 * 4;
    float* gcnt   = (float*)ws;   ws += NB * 4;
    int* csr      = (int*)ws;     ws += (size_t)NN * 4;
    float* zsum   = (float*)ws;   ws += 4 * 64 * 4;
    float* G      = (float*)ws;   ws += (size_t)4 * 8192 * 4;  // per-layer [Ghh|Ghl]
    size_t zbytes = (size_t)(ws - (char*)d_ws);
    // ---- rest ----
    int* bsum       = (int*)ws;       ws += 128 * 4;
    unsigned* epack = (unsigned*)ws;  ws += (size_t)NE * 4;
    float* Gpart = (float*)ws;    ws += (size_t)NZB * 8192 * 4;
    float* xbuf = (float*)ws;     ws += (size_t)NN * 64 * 4;   // h (l=0) / t2 (l>=1), fp32
    unsigned short* x16 = (unsigned short*)ws; ws += (size_t)NN * 64 * 2;  // bf16 mirror
    float* agg  = (float*)ws;     ws += (size_t)NN * 64 * 4;
    unsigned short* w1h = (unsigned short*)ws; ws += 32768 * 2;
    unsigned short* w2h = (unsigned short*)ws; ws += 32768 * 2;

    hipMemsetAsync((void*)stats, 0, zbytes, stream);

    wcvt<<<256, 256, 0, stream>>>(W1, W2, w1h, w2h);
    deg_count<<<4883, 256, 0, stream>>>(edge_index, csr);
    scan_local<<<98, 256, 0, stream>>>(csr, bsum);
    scan_bsum<<<1, 128, 0, stream>>>(bsum);
    scan_add<<<98, 256, 0, stream>>>(csr, bsum);
    csr_fill<<<4883 * 8, 256, 0, stream>>>(edge_index, edge_attr, csr, epack);
    atom_encode<<<6250, 256, 0, stream>>>(atom_emb, x_feat, xbuf, x16);

    for (int l = 0; l < 4; l++) {
        double* s1 = stats + (size_t)(l * 2) * 256;
        double* s2 = stats + (size_t)(l * 2 + 1) * 256;
        if (l == 0) {
            gather_k<false><<<6250, 256, 0, stream>>>(xbuf, x16, bond_emb, eps, csr, epack, l,
                                                      nullptr, nullptr, nullptr, agg);
        } else {
            double* sp = stats + (size_t)((l - 1) * 2 + 1) * 256;
            gather_k<true><<<6250, 256, 0, stream>>>(xbuf, x16, bond_emb, eps, csr, epack, l,
                                                     sp, bn2_g, bn2_b, agg);
        }
        float* Gl = G + (size_t)l * 8192;
        zstat<<<NZB, 256, 0, stream>>>(agg, Gpart, zsum + l * 64);
        greduce<<<dim3(32, 4), 256, 0, stream>>>(Gpart, Gl);
        bn1stat<<<128, 256, 0, stream>>>(W1, b1, Gl, zsum + l * 64, l, s1);
        mlp_fused<<<1563, 256, 0, stream>>>(agg, w1h, b1, w2h, b2,
                                            bn1_g, bn1_b, s1, l, xbuf, x16, s2);
    }
    bnapply_last<<<1563, 256, 0, stream>>>(xbuf, bn2_g, bn2_b,
                                           stats + (size_t)(3 * 2 + 1) * 256,
                                           out, gsum, gcnt, batch);
    pool_div<<<512, 256, 0, stream>>>(gsum, gcnt, out);
}